// Round 1
// baseline (861.517 us; speedup 1.0000x reference)
//
#include <hip/hip_runtime.h>

typedef unsigned short u16;
typedef __attribute__((ext_vector_type(8))) short bf16x8;
typedef __attribute__((ext_vector_type(4))) float f32x4;

constexpr int NN = 50000;   // nodes
constexpr int NE = 800000;  // edges
constexpr int LM = 1024;
constexpr int HC = 128;
constexpr int OC = 64;

// ---- workspace layout (bytes, all 256-aligned) ----
constexpr size_t OFF_ROWPTR = 0;          // (NN+1) int
constexpr size_t OFF_CURSOR = 200192;     // NN int
constexpr size_t OFF_COUNTS = 400384;     // NN int
constexpr size_t OFF_INCL   = 600576;     // NN int
constexpr size_t OFF_BSUM   = 800768;     // 64 int
constexpr size_t OFF_BOFF   = 801024;     // 64 int
constexpr size_t OFF_DIS    = 801280;     // NN float
constexpr size_t OFF_CSRC   = 1001472;    // NE int
constexpr size_t OFF_CSW    = 4201472;    // NE float
constexpr size_t OFF_WLT    = 7401472;    // LM*LM u16
constexpr size_t OFF_W1T    = 9498624;    // HC*LM u16
constexpr size_t OFF_H      = 9760768;    // NN*LM u16
constexpr size_t OFF_Y1     = 112160768;  // NN*HC u16
constexpr size_t OFF_H1     = 124960768;  // NN*HC u16
constexpr size_t OFF_Y3     = 137760768;  // NN*OC u16
// total = 144160768 bytes (~137.5 MB)

__device__ __forceinline__ u16 f2bf(float f) {
    union { float f; unsigned int u; } a; a.f = f;
    unsigned int u = a.u + 0x7FFFu + ((a.u >> 16) & 1u);  // RNE
    return (u16)(u >> 16);
}
__device__ __forceinline__ float bf2f(u16 v) {
    union { unsigned int u; float f; } a; a.u = ((unsigned int)v) << 16;
    return a.f;
}
__device__ __forceinline__ void async_copy16(u16* lds, const u16* g) {
    __builtin_amdgcn_global_load_lds(
        (const __attribute__((address_space(1))) void*)g,
        (__attribute__((address_space(3))) void*)lds, 16, 0, 0);
}

// ================= CSR build =================
__global__ void k_zero(int* counts) {
    int i = blockIdx.x * 256 + threadIdx.x;
    if (i < NN) counts[i] = 0;
}
__global__ void k_count(const int* __restrict__ ei, int* __restrict__ counts) {
    int e = blockIdx.x * 256 + threadIdx.x;
    if (e < NE) atomicAdd(&counts[ei[NE + e]], 1);
}
__global__ void k_scan1(const int* __restrict__ counts, int* __restrict__ incl,
                        int* __restrict__ bsum) {
    __shared__ int sm[1024];
    int t = threadIdx.x, idx = blockIdx.x * 1024 + t;
    int v = (idx < NN) ? counts[idx] : 0;
    sm[t] = v; __syncthreads();
    for (int off = 1; off < 1024; off <<= 1) {
        int add = (t >= off) ? sm[t - off] : 0;
        __syncthreads();
        sm[t] += add;
        __syncthreads();
    }
    if (idx < NN) incl[idx] = sm[t];
    if (t == 1023) bsum[blockIdx.x] = sm[t];
}
__global__ void k_scan2(const int* __restrict__ bsum, int* __restrict__ boff, int nb) {
    if (threadIdx.x == 0 && blockIdx.x == 0) {
        int run = 0;
        for (int i = 0; i < nb; i++) { boff[i] = run; run += bsum[i]; }
    }
}
__global__ void k_scan3(const int* __restrict__ incl, const int* __restrict__ counts,
                        const int* __restrict__ boff, int* __restrict__ rowptr,
                        int* __restrict__ cursor) {
    int idx = blockIdx.x * 256 + threadIdx.x;
    if (idx < NN) {
        int rp = incl[idx] - counts[idx] + boff[idx >> 10];
        rowptr[idx] = rp;
        cursor[idx] = rp;
    } else if (idx == NN) {
        rowptr[NN] = NE;
    }
}
__global__ void k_fill(const int* __restrict__ ei, const float* __restrict__ ew,
                       int* __restrict__ cursor, int* __restrict__ csrc,
                       float* __restrict__ csw) {
    int e = blockIdx.x * 256 + threadIdx.x;
    if (e < NE) {
        int d = ei[NE + e];
        int slot = atomicAdd(&cursor[d], 1);
        csrc[slot] = ei[e];
        csw[slot] = ew[e];
    }
}
__global__ void k_deg(const int* __restrict__ rowptr, const float* __restrict__ csw,
                      float* __restrict__ dis) {
    int i = blockIdx.x * 256 + threadIdx.x;
    if (i >= NN) return;
    float d = 1.0f;  // self loop weight
    int p1 = rowptr[i + 1];
    for (int p = rowptr[i]; p < p1; ++p) d += csw[p];
    dis[i] = rsqrtf(d);
}

// ================= weight conversion =================
__global__ void k_cvtWl(const float* __restrict__ Wl, u16* __restrict__ WlT) {
    __shared__ float sm[32][33];
    int k0 = blockIdx.y * 32, n0 = blockIdx.x * 32;
    sm[threadIdx.y][threadIdx.x] = Wl[(size_t)(k0 + threadIdx.y) * LM + n0 + threadIdx.x];
    __syncthreads();
    WlT[(size_t)(n0 + threadIdx.y) * LM + k0 + threadIdx.x] = f2bf(sm[threadIdx.x][threadIdx.y]);
}
__global__ void k_cvtW1(const float* __restrict__ W1, u16* __restrict__ W1T) {
    int idx = blockIdx.x * 256 + threadIdx.x;  // HC*LM, output-major
    if (idx >= HC * LM) return;
    int o = idx >> 10, k = idx & 1023;
    W1T[idx] = f2bf(W1[(size_t)k * HC + o]);
}

// ================= MFMA GEMM (m97-style 128x128 tile, BK=64) =================
// MODE 1: A fp32 (converted in staging), epilogue relu(acc + x*Wa + c*Wc + bl)
// MODE 2: A bf16 (async global_load_lds), raw acc
template <int MODE>
__global__ __launch_bounds__(256, 2) void k_gemm(
    const void* __restrict__ Aptr, const u16* __restrict__ Bt, u16* __restrict__ Cout,
    int M, int Nn, int K, int nby,
    const float* __restrict__ xv, const float* __restrict__ cv,
    const float* __restrict__ Wa, const float* __restrict__ Wc,
    const float* __restrict__ bl) {
    __shared__ u16 lA[128 * 64];
    __shared__ u16 lB[128 * 64];
    const int tid = threadIdx.x;
    const int lane = tid & 63, wv = tid >> 6;
    const int by = blockIdx.x % nby, bx = blockIdx.x / nby;  // by fastest: A-band L2 reuse
    const int m0 = bx * 128, n0 = by * 128;
    const int wm = (wv >> 1) * 64, wn = (wv & 1) * 64;
    const int fr = lane & 15, qd = lane >> 4;

    f32x4 acc[4][4] = {};

    for (int k0 = 0; k0 < K; k0 += 64) {
        __syncthreads();
        // stage B^T tile [128 cols][64 k] via async direct-to-LDS
        #pragma unroll
        for (int i = 0; i < 4; i++) {
            int cl = i * 32 + wv * 8 + (lane >> 3);
            int col = n0 + cl; if (col >= Nn) col = Nn - 1;
            const u16* g = Bt + (size_t)col * K + k0 + (lane & 7) * 8;
            async_copy16(&lB[(i * 32 + wv * 8) * 64], g);
        }
        if constexpr (MODE == 2) {
            #pragma unroll
            for (int i = 0; i < 4; i++) {
                int rl = i * 32 + wv * 8 + (lane >> 3);
                int row = m0 + rl; if (row >= M) row = M - 1;
                const u16* g = (const u16*)Aptr + (size_t)row * K + k0 + (lane & 7) * 8;
                async_copy16(&lA[(i * 32 + wv * 8) * 64], g);
            }
        } else {
            const float* A32 = (const float*)Aptr;
            #pragma unroll
            for (int i = 0; i < 8; i++) {
                int f = i * 256 + tid;          // float4 id within 128x64 tile
                int rl = f >> 4, c4 = f & 15;
                int row = m0 + rl; if (row >= M) row = M - 1;
                float4 v = *(const float4*)(A32 + (size_t)row * K + k0 + c4 * 4);
                ushort4 u;
                u.x = f2bf(v.x); u.y = f2bf(v.y); u.z = f2bf(v.z); u.w = f2bf(v.w);
                *(ushort4*)&lA[rl * 64 + c4 * 4] = u;
            }
        }
        __syncthreads();
        #pragma unroll
        for (int s = 0; s < 2; s++) {
            bf16x8 af[4], bfm[4];
            #pragma unroll
            for (int mi = 0; mi < 4; mi++)
                af[mi] = *(const bf16x8*)&lA[(wm + mi * 16 + fr) * 64 + s * 32 + qd * 8];
            #pragma unroll
            for (int ni = 0; ni < 4; ni++)
                bfm[ni] = *(const bf16x8*)&lB[(wn + ni * 16 + fr) * 64 + s * 32 + qd * 8];
            #pragma unroll
            for (int mi = 0; mi < 4; mi++)
                #pragma unroll
                for (int ni = 0; ni < 4; ni++)
                    acc[mi][ni] = __builtin_amdgcn_mfma_f32_16x16x32_bf16(
                        af[mi], bfm[ni], acc[mi][ni], 0, 0, 0);
        }
    }

    // epilogue: C/D layout col=lane&15, row=(lane>>4)*4+reg
    int jj[4]; float waj[4], wcj[4], blj[4];
    #pragma unroll
    for (int ni = 0; ni < 4; ni++) {
        jj[ni] = n0 + wn + ni * 16 + fr;
        if constexpr (MODE == 1) { waj[ni] = Wa[jj[ni]]; wcj[ni] = Wc[jj[ni]]; blj[ni] = bl[jj[ni]]; }
    }
    #pragma unroll
    for (int mi = 0; mi < 4; mi++) {
        #pragma unroll
        for (int r = 0; r < 4; r++) {
            int row = m0 + wm + mi * 16 + qd * 4 + r;
            if (row < M) {
                float xb = 0.f, cb = 0.f;
                if constexpr (MODE == 1) { xb = xv[row]; cb = cv[row]; }
                #pragma unroll
                for (int ni = 0; ni < 4; ni++) {
                    float v = acc[mi][ni][r];
                    if constexpr (MODE == 1) {
                        v += xb * waj[ni] + cb * wcj[ni] + blj[ni];
                        v = fmaxf(v, 0.f);
                    }
                    Cout[(size_t)row * Nn + jj[ni]] = f2bf(v);
                }
            }
        }
    }
}

// ================= aggregation 1: h1 = relu(Anorm @ y1 + b1), HC=128 =================
__global__ __launch_bounds__(256) void k_agg1(
    const u16* __restrict__ y1, const int* __restrict__ rowptr,
    const int* __restrict__ csrc, const float* __restrict__ csw,
    const float* __restrict__ dis, const float* __restrict__ b1,
    u16* __restrict__ h1) {
    int node = blockIdx.x * 4 + (threadIdx.x >> 6);
    int lane = threadIdx.x & 63;
    if (node >= NN) return;
    float di = dis[node];
    int p0 = rowptr[node], p1 = rowptr[node + 1];
    ushort2 sv = *(const ushort2*)(y1 + (size_t)node * HC + lane * 2);
    float a0 = di * di * bf2f(sv.x), a1 = di * di * bf2f(sv.y);
    for (int p = p0; p < p1; ++p) {
        int s = csrc[p];
        float nm = dis[s] * csw[p] * di;
        ushort2 v = *(const ushort2*)(y1 + (size_t)s * HC + lane * 2);
        a0 += nm * bf2f(v.x);
        a1 += nm * bf2f(v.y);
    }
    a0 = fmaxf(a0 + b1[lane * 2], 0.f);
    a1 = fmaxf(a1 + b1[lane * 2 + 1], 0.f);
    ushort2 r; r.x = f2bf(a0); r.y = f2bf(a1);
    *(ushort2*)(h1 + (size_t)node * HC + lane * 2) = r;
}

// ================= GEMM3: y3 = h1 @ W3 (K=128 -> 64), vector ALU =================
__global__ __launch_bounds__(256) void k_gemm3(
    const u16* __restrict__ h1, const float* __restrict__ W3, u16* __restrict__ y3) {
    int node = blockIdx.x * 4 + (threadIdx.x >> 6);
    int o = threadIdx.x & 63;
    if (node >= NN) return;
    const u16* hrow = h1 + (size_t)node * HC;
    float acc = 0.f;
    #pragma unroll 16
    for (int k = 0; k < HC; ++k)
        acc += bf2f(hrow[k]) * W3[(size_t)k * OC + o];
    y3[(size_t)node * OC + o] = f2bf(acc);
}

// ================= aggregation 3: out = Anorm @ y3 + b3, OC=64 =================
__global__ __launch_bounds__(256) void k_agg3(
    const u16* __restrict__ y3, const int* __restrict__ rowptr,
    const int* __restrict__ csrc, const float* __restrict__ csw,
    const float* __restrict__ dis, const float* __restrict__ b3,
    float* __restrict__ outp) {
    int node = blockIdx.x * 4 + (threadIdx.x >> 6);
    int lane = threadIdx.x & 63;
    if (node >= NN) return;
    float di = dis[node];
    int p0 = rowptr[node], p1 = rowptr[node + 1];
    float a = di * di * bf2f(y3[(size_t)node * OC + lane]);
    for (int p = p0; p < p1; ++p) {
        int s = csrc[p];
        float nm = dis[s] * csw[p] * di;
        a += nm * bf2f(y3[(size_t)s * OC + lane]);
    }
    outp[(size_t)node * OC + lane] = a + b3[lane];
}

extern "C" void kernel_launch(void* const* d_in, const int* in_sizes, int n_in,
                              void* d_out, int out_size, void* d_ws, size_t ws_size,
                              hipStream_t stream) {
    const float* x    = (const float*)d_in[0];
    const float* xout = (const float*)d_in[1];
    const float* c    = (const float*)d_in[2];
    const int*   ei   = (const int*)d_in[3];
    const float* ew   = (const float*)d_in[4];
    const float* Wa   = (const float*)d_in[5];
    const float* Wc   = (const float*)d_in[6];
    const float* Wl   = (const float*)d_in[7];
    const float* bl   = (const float*)d_in[8];
    const float* W1   = (const float*)d_in[9];
    const float* b1   = (const float*)d_in[10];
    const float* W3   = (const float*)d_in[11];
    const float* b3   = (const float*)d_in[12];
    float* outp = (float*)d_out;

    char* ws = (char*)d_ws;
    int*   rowptr = (int*)(ws + OFF_ROWPTR);
    int*   cursor = (int*)(ws + OFF_CURSOR);
    int*   counts = (int*)(ws + OFF_COUNTS);
    int*   incl   = (int*)(ws + OFF_INCL);
    int*   bsum   = (int*)(ws + OFF_BSUM);
    int*   boff   = (int*)(ws + OFF_BOFF);
    float* dis    = (float*)(ws + OFF_DIS);
    int*   csrc   = (int*)(ws + OFF_CSRC);
    float* csw    = (float*)(ws + OFF_CSW);
    u16*   WlT    = (u16*)(ws + OFF_WLT);
    u16*   W1T    = (u16*)(ws + OFF_W1T);
    u16*   hbuf   = (u16*)(ws + OFF_H);
    u16*   y1     = (u16*)(ws + OFF_Y1);
    u16*   h1     = (u16*)(ws + OFF_H1);
    u16*   y3     = (u16*)(ws + OFF_Y3);

    // CSR build
    k_zero <<<196, 256, 0, stream>>>(counts);
    k_count<<<3125, 256, 0, stream>>>(ei, counts);
    k_scan1<<<49, 1024, 0, stream>>>(counts, incl, bsum);
    k_scan2<<<1, 64, 0, stream>>>(bsum, boff, 49);
    k_scan3<<<196, 256, 0, stream>>>(incl, counts, boff, rowptr, cursor);
    k_fill <<<3125, 256, 0, stream>>>(ei, ew, cursor, csrc, csw);
    k_deg  <<<196, 256, 0, stream>>>(rowptr, csw, dis);

    // weight conversion (bf16, transposed to [out, K])
    k_cvtWl<<<dim3(32, 32), dim3(32, 32), 0, stream>>>(Wl, WlT);
    k_cvtW1<<<512, 256, 0, stream>>>(W1, W1T);

    // GEMM1: h = relu(x_out@Wl + x*Wa + c*Wc + bl)   [N, 1024]
    k_gemm<1><<<391 * 8, 256, 0, stream>>>(xout, WlT, hbuf, NN, LM, LM, 8,
                                           x, c, Wa, Wc, bl);
    // GEMM2: y1 = h @ W1   [N, 128]
    k_gemm<2><<<391, 256, 0, stream>>>(hbuf, W1T, y1, NN, HC, LM, 1,
                                       nullptr, nullptr, nullptr, nullptr, nullptr);
    // conv1 aggregation + bias + relu
    k_agg1<<<12500, 256, 0, stream>>>(y1, rowptr, csrc, csw, dis, b1, h1);
    // GEMM3: y3 = h1 @ W3   [N, 64]
    k_gemm3<<<12500, 256, 0, stream>>>(h1, W3, y3);
    // conv3 aggregation + bias -> out
    k_agg3<<<12500, 256, 0, stream>>>(y3, rowptr, csrc, csw, dis, b3, outp);
}

// Round 2
// 801.093 us; speedup vs baseline: 1.0754x; 1.0754x over previous
//
#include <hip/hip_runtime.h>
#include <hip/hip_bf16.h>

typedef unsigned short u16;
typedef __attribute__((ext_vector_type(8))) short bf16x8;
typedef __attribute__((ext_vector_type(4))) float f32x4;

constexpr int NN = 50000;   // nodes
constexpr int NE = 800000;  // edges
constexpr int LM = 1024;
constexpr int HC = 128;
constexpr int OC = 64;

// ---- workspace layout (bytes, all 256-aligned) ----
constexpr size_t OFF_ROWPTR = 0;          // (NN+1) int
constexpr size_t OFF_CURSOR = 200192;     // NN int
constexpr size_t OFF_COUNTS = 400384;     // NN int
constexpr size_t OFF_INCL   = 600576;     // NN int
constexpr size_t OFF_BSUM   = 800768;     // 64 int
constexpr size_t OFF_BOFF   = 801024;     // 64 int
constexpr size_t OFF_DIS    = 801280;     // NN float
constexpr size_t OFF_CSRC   = 1001472;    // NE int
constexpr size_t OFF_CSW    = 4201472;    // NE float
constexpr size_t OFF_WLT    = 7401472;    // LM*LM u16
constexpr size_t OFF_W1T    = 9498624;    // HC*LM u16
constexpr size_t OFF_H      = 9760768;    // NN*LM u16
constexpr size_t OFF_Y1     = 112160768;  // NN*HC u16
constexpr size_t OFF_H1     = 124960768;  // NN*HC u16
constexpr size_t OFF_Y3     = 137760768;  // NN*OC u16
// total = 144160768 bytes (~137.5 MB)

__device__ __forceinline__ u16 f2bf(float f) {
    union { float f; unsigned int u; } a; a.f = f;
    unsigned int u = a.u + 0x7FFFu + ((a.u >> 16) & 1u);  // RNE
    return (u16)(u >> 16);
}
__device__ __forceinline__ float bf2f(u16 v) {
    union { unsigned int u; float f; } a; a.u = ((unsigned int)v) << 16;
    return a.f;
}
__device__ __forceinline__ ushort2 pkbf(float a, float b) {
    union { __hip_bfloat162 h; ushort2 u; } cv;
    cv.h = __float22bfloat162_rn(make_float2(a, b));
    return cv.u;
}
__device__ __forceinline__ void async_copy16(u16* lds, const u16* g) {
    __builtin_amdgcn_global_load_lds(
        (const __attribute__((address_space(1))) void*)g,
        (__attribute__((address_space(3))) void*)lds, 16, 0, 0);
}

// ================= CSR build =================
__global__ void k_zero(int* counts) {
    int i = blockIdx.x * 256 + threadIdx.x;
    if (i < NN) counts[i] = 0;
}
__global__ void k_count(const int* __restrict__ ei, int* __restrict__ counts) {
    int e = blockIdx.x * 256 + threadIdx.x;
    if (e < NE) atomicAdd(&counts[ei[NE + e]], 1);
}
__global__ void k_scan1(const int* __restrict__ counts, int* __restrict__ incl,
                        int* __restrict__ bsum) {
    __shared__ int sm[1024];
    int t = threadIdx.x, idx = blockIdx.x * 1024 + t;
    int v = (idx < NN) ? counts[idx] : 0;
    sm[t] = v; __syncthreads();
    for (int off = 1; off < 1024; off <<= 1) {
        int add = (t >= off) ? sm[t - off] : 0;
        __syncthreads();
        sm[t] += add;
        __syncthreads();
    }
    if (idx < NN) incl[idx] = sm[t];
    if (t == 1023) bsum[blockIdx.x] = sm[t];
}
__global__ void k_scan2(const int* __restrict__ bsum, int* __restrict__ boff, int nb) {
    if (threadIdx.x == 0 && blockIdx.x == 0) {
        int run = 0;
        for (int i = 0; i < nb; i++) { boff[i] = run; run += bsum[i]; }
    }
}
__global__ void k_scan3(const int* __restrict__ incl, const int* __restrict__ counts,
                        const int* __restrict__ boff, int* __restrict__ rowptr,
                        int* __restrict__ cursor) {
    int idx = blockIdx.x * 256 + threadIdx.x;
    if (idx < NN) {
        int rp = incl[idx] - counts[idx] + boff[idx >> 10];
        rowptr[idx] = rp;
        cursor[idx] = rp;
    } else if (idx == NN) {
        rowptr[NN] = NE;
    }
}
__global__ void k_fill(const int* __restrict__ ei, const float* __restrict__ ew,
                       int* __restrict__ cursor, int* __restrict__ csrc,
                       float* __restrict__ csw) {
    int e = blockIdx.x * 256 + threadIdx.x;
    if (e < NE) {
        int d = ei[NE + e];
        int slot = atomicAdd(&cursor[d], 1);
        csrc[slot] = ei[e];
        csw[slot] = ew[e];
    }
}
__global__ void k_deg(const int* __restrict__ rowptr, const float* __restrict__ csw,
                      float* __restrict__ dis) {
    int i = blockIdx.x * 256 + threadIdx.x;
    if (i >= NN) return;
    float d = 1.0f;  // self loop weight
    int p1 = rowptr[i + 1];
    for (int p = rowptr[i]; p < p1; ++p) d += csw[p];
    dis[i] = rsqrtf(d);
}

// ================= weight conversion =================
__global__ void k_cvtWl(const float* __restrict__ Wl, u16* __restrict__ WlT) {
    __shared__ float sm[32][33];
    int k0 = blockIdx.y * 32, n0 = blockIdx.x * 32;
    sm[threadIdx.y][threadIdx.x] = Wl[(size_t)(k0 + threadIdx.y) * LM + n0 + threadIdx.x];
    __syncthreads();
    WlT[(size_t)(n0 + threadIdx.y) * LM + k0 + threadIdx.x] = f2bf(sm[threadIdx.x][threadIdx.y]);
}
__global__ void k_cvtW1(const float* __restrict__ W1, u16* __restrict__ W1T) {
    int idx = blockIdx.x * 256 + threadIdx.x;  // HC*LM, output-major
    if (idx >= HC * LM) return;
    int o = idx >> 10, k = idx & 1023;
    W1T[idx] = f2bf(W1[(size_t)k * HC + o]);
}

// ================= MFMA GEMM (128x128 tile, BK=64, XOR-swizzled LDS) =================
// LDS tile layout: 16B chunk (row rl, k-chunk k8) stored at chunk slot
// rl*8 + (k8 ^ (rl&7)). Keeps each row's chunks inside its 128B block (so
// global_load_lds lane*16 scatter still works) while rotating banks per row:
// frag reads (lanes 0..15 = rows fr) hit banks (slot*4..+3), slot = k8^(fr&7)
// -> 8 distinct bank quads -> only free 2-way aliasing. [R1: kills 3.8e7
// SQ_LDS_BANK_CONFLICT cycles observed in R0]
// MODE 1: A fp32 (converted in staging), epilogue relu(acc + x*Wa + c*Wc + bl)
// MODE 2: A bf16 (async global_load_lds), raw acc
template <int MODE>
__global__ __launch_bounds__(256, 2) void k_gemm(
    const void* __restrict__ Aptr, const u16* __restrict__ Bt, u16* __restrict__ Cout,
    int M, int Nn, int K, int nby,
    const float* __restrict__ xv, const float* __restrict__ cv,
    const float* __restrict__ Wa, const float* __restrict__ Wc,
    const float* __restrict__ bl) {
    __shared__ u16 lA[128 * 64];
    __shared__ u16 lB[128 * 64];
    const int tid = threadIdx.x;
    const int lane = tid & 63, wv = tid >> 6;
    const int mtiles = (M + 127) >> 7;
    int bx, by;
    if (nby > 1) {
        // XCD swizzle: the nby sibling blocks of one m-band get IDs == same
        // value mod 8 and adjacent dispatch slots -> same XCD, A-band L2 reuse.
        int x = blockIdx.x & 7, j = blockIdx.x >> 3;
        bx = (j & ~7) | x;
        by = j & 7;
        if (bx >= mtiles) return;  // uniform across block, before any barrier
    } else {
        bx = blockIdx.x; by = 0;
    }
    const int m0 = bx * 128, n0 = by * 128;
    const int wm = (wv >> 1) * 64, wn = (wv & 1) * 64;
    const int fr = lane & 15, qd = lane >> 4;

    f32x4 acc[4][4] = {};

    for (int k0 = 0; k0 < K; k0 += 64) {
        __syncthreads();
        // stage B^T tile [128 cols][64 k] via async direct-to-LDS, XOR swizzle
        #pragma unroll
        for (int i = 0; i < 4; i++) {
            int r0 = i * 32 + wv * 8;
            int rl = r0 + (lane >> 3);
            int slot = lane & 7;
            int k8 = slot ^ (rl & 7);
            int col = n0 + rl; if (col >= Nn) col = Nn - 1;
            const u16* g = Bt + (size_t)col * K + k0 + k8 * 8;
            async_copy16(&lB[r0 * 64], g);
        }
        if constexpr (MODE == 2) {
            #pragma unroll
            for (int i = 0; i < 4; i++) {
                int r0 = i * 32 + wv * 8;
                int rl = r0 + (lane >> 3);
                int slot = lane & 7;
                int k8 = slot ^ (rl & 7);
                int row = m0 + rl; if (row >= M) row = M - 1;
                const u16* g = (const u16*)Aptr + (size_t)row * K + k0 + k8 * 8;
                async_copy16(&lA[r0 * 64], g);
            }
        } else {
            const float* A32 = (const float*)Aptr;
            #pragma unroll
            for (int i = 0; i < 4; i++) {
                int cidx = i * 256 + tid;          // chunk id within 128x64 tile
                int rl = cidx >> 3, slot = cidx & 7;
                int k8 = slot ^ (rl & 7);
                int row = m0 + rl; if (row >= M) row = M - 1;
                const float* src = A32 + (size_t)row * K + k0 + k8 * 8;
                float4 v0 = *(const float4*)(src);
                float4 v1 = *(const float4*)(src + 4);
                union { ushort2 u2[4]; bf16x8 v; } pk;
                pk.u2[0] = pkbf(v0.x, v0.y);
                pk.u2[1] = pkbf(v0.z, v0.w);
                pk.u2[2] = pkbf(v1.x, v1.y);
                pk.u2[3] = pkbf(v1.z, v1.w);
                *(bf16x8*)&lA[rl * 64 + slot * 8] = pk.v;
            }
        }
        __syncthreads();
        #pragma unroll
        for (int s = 0; s < 2; s++) {
            const int slot = (s * 4 + qd) ^ (fr & 7);  // same for A and B frags
            bf16x8 af[4], bfm[4];
            #pragma unroll
            for (int mi = 0; mi < 4; mi++)
                af[mi] = *(const bf16x8*)&lA[(wm + mi * 16 + fr) * 64 + slot * 8];
            #pragma unroll
            for (int ni = 0; ni < 4; ni++)
                bfm[ni] = *(const bf16x8*)&lB[(wn + ni * 16 + fr) * 64 + slot * 8];
            #pragma unroll
            for (int mi = 0; mi < 4; mi++)
                #pragma unroll
                for (int ni = 0; ni < 4; ni++)
                    acc[mi][ni] = __builtin_amdgcn_mfma_f32_16x16x32_bf16(
                        af[mi], bfm[ni], acc[mi][ni], 0, 0, 0);
        }
    }

    // epilogue: C/D layout col=lane&15, row=(lane>>4)*4+reg
    int jj[4]; float waj[4], wcj[4], blj[4];
    #pragma unroll
    for (int ni = 0; ni < 4; ni++) {
        jj[ni] = n0 + wn + ni * 16 + fr;
        if constexpr (MODE == 1) { waj[ni] = Wa[jj[ni]]; wcj[ni] = Wc[jj[ni]]; blj[ni] = bl[jj[ni]]; }
    }
    #pragma unroll
    for (int mi = 0; mi < 4; mi++) {
        #pragma unroll
        for (int r = 0; r < 4; r++) {
            int row = m0 + wm + mi * 16 + qd * 4 + r;
            if (row < M) {
                float xb = 0.f, cb = 0.f;
                if constexpr (MODE == 1) { xb = xv[row]; cb = cv[row]; }
                #pragma unroll
                for (int ni = 0; ni < 4; ni++) {
                    float v = acc[mi][ni][r];
                    if constexpr (MODE == 1) {
                        v += xb * waj[ni] + cb * wcj[ni] + blj[ni];
                        v = fmaxf(v, 0.f);
                    }
                    Cout[(size_t)row * Nn + jj[ni]] = f2bf(v);
                }
            }
        }
    }
}

// ================= aggregation 1: h1 = relu(Anorm @ y1 + b1), HC=128 =================
__global__ __launch_bounds__(256) void k_agg1(
    const u16* __restrict__ y1, const int* __restrict__ rowptr,
    const int* __restrict__ csrc, const float* __restrict__ csw,
    const float* __restrict__ dis, const float* __restrict__ b1,
    u16* __restrict__ h1) {
    int node = blockIdx.x * 4 + (threadIdx.x >> 6);
    int lane = threadIdx.x & 63;
    if (node >= NN) return;
    float di = dis[node];
    int p0 = rowptr[node], p1 = rowptr[node + 1];
    ushort2 sv = *(const ushort2*)(y1 + (size_t)node * HC + lane * 2);
    float a0 = di * di * bf2f(sv.x), a1 = di * di * bf2f(sv.y);
    for (int p = p0; p < p1; ++p) {
        int s = csrc[p];
        float nm = dis[s] * csw[p] * di;
        ushort2 v = *(const ushort2*)(y1 + (size_t)s * HC + lane * 2);
        a0 += nm * bf2f(v.x);
        a1 += nm * bf2f(v.y);
    }
    a0 = fmaxf(a0 + b1[lane * 2], 0.f);
    a1 = fmaxf(a1 + b1[lane * 2 + 1], 0.f);
    ushort2 r; r.x = f2bf(a0); r.y = f2bf(a1);
    *(ushort2*)(h1 + (size_t)node * HC + lane * 2) = r;
}

// ================= GEMM3: y3 = h1 @ W3 (K=128 -> 64), vector ALU =================
__global__ __launch_bounds__(256) void k_gemm3(
    const u16* __restrict__ h1, const float* __restrict__ W3, u16* __restrict__ y3) {
    int node = blockIdx.x * 4 + (threadIdx.x >> 6);
    int o = threadIdx.x & 63;
    if (node >= NN) return;
    const u16* hrow = h1 + (size_t)node * HC;
    float acc = 0.f;
    #pragma unroll 16
    for (int k = 0; k < HC; ++k)
        acc += bf2f(hrow[k]) * W3[(size_t)k * OC + o];
    y3[(size_t)node * OC + o] = f2bf(acc);
}

// ================= aggregation 3: out = Anorm @ y3 + b3, OC=64 =================
__global__ __launch_bounds__(256) void k_agg3(
    const u16* __restrict__ y3, const int* __restrict__ rowptr,
    const int* __restrict__ csrc, const float* __restrict__ csw,
    const float* __restrict__ dis, const float* __restrict__ b3,
    float* __restrict__ outp) {
    int node = blockIdx.x * 4 + (threadIdx.x >> 6);
    int lane = threadIdx.x & 63;
    if (node >= NN) return;
    float di = dis[node];
    int p0 = rowptr[node], p1 = rowptr[node + 1];
    float a = di * di * bf2f(y3[(size_t)node * OC + lane]);
    for (int p = p0; p < p1; ++p) {
        int s = csrc[p];
        float nm = dis[s] * csw[p] * di;
        a += nm * bf2f(y3[(size_t)s * OC + lane]);
    }
    outp[(size_t)node * OC + lane] = a + b3[lane];
}

extern "C" void kernel_launch(void* const* d_in, const int* in_sizes, int n_in,
                              void* d_out, int out_size, void* d_ws, size_t ws_size,
                              hipStream_t stream) {
    const float* x    = (const float*)d_in[0];
    const float* xout = (const float*)d_in[1];
    const float* c    = (const float*)d_in[2];
    const int*   ei   = (const int*)d_in[3];
    const float* ew   = (const float*)d_in[4];
    const float* Wa   = (const float*)d_in[5];
    const float* Wc   = (const float*)d_in[6];
    const float* Wl   = (const float*)d_in[7];
    const float* bl   = (const float*)d_in[8];
    const float* W1   = (const float*)d_in[9];
    const float* b1   = (const float*)d_in[10];
    const float* W3   = (const float*)d_in[11];
    const float* b3   = (const float*)d_in[12];
    float* outp = (float*)d_out;

    char* ws = (char*)d_ws;
    int*   rowptr = (int*)(ws + OFF_ROWPTR);
    int*   cursor = (int*)(ws + OFF_CURSOR);
    int*   counts = (int*)(ws + OFF_COUNTS);
    int*   incl   = (int*)(ws + OFF_INCL);
    int*   bsum   = (int*)(ws + OFF_BSUM);
    int*   boff   = (int*)(ws + OFF_BOFF);
    float* dis    = (float*)(ws + OFF_DIS);
    int*   csrc   = (int*)(ws + OFF_CSRC);
    float* csw    = (float*)(ws + OFF_CSW);
    u16*   WlT    = (u16*)(ws + OFF_WLT);
    u16*   W1T    = (u16*)(ws + OFF_W1T);
    u16*   hbuf   = (u16*)(ws + OFF_H);
    u16*   y1     = (u16*)(ws + OFF_Y1);
    u16*   h1     = (u16*)(ws + OFF_H1);
    u16*   y3     = (u16*)(ws + OFF_Y3);

    // CSR build
    k_zero <<<196, 256, 0, stream>>>(counts);
    k_count<<<3125, 256, 0, stream>>>(ei, counts);
    k_scan1<<<49, 1024, 0, stream>>>(counts, incl, bsum);
    k_scan2<<<1, 64, 0, stream>>>(bsum, boff, 49);
    k_scan3<<<196, 256, 0, stream>>>(incl, counts, boff, rowptr, cursor);
    k_fill <<<3125, 256, 0, stream>>>(ei, ew, cursor, csrc, csw);
    k_deg  <<<196, 256, 0, stream>>>(rowptr, csw, dis);

    // weight conversion (bf16, transposed to [out, K])
    k_cvtWl<<<dim3(32, 32), dim3(32, 32), 0, stream>>>(Wl, WlT);
    k_cvtW1<<<512, 256, 0, stream>>>(W1, W1T);

    // GEMM1: h = relu(x_out@Wl + x*Wa + c*Wc + bl)   [N, 1024]
    // grid 392*8: j=bid>>3 in [0,392) -> bx=(j&~7)|(bid&7) covers 0..391, guard trims
    k_gemm<1><<<392 * 8, 256, 0, stream>>>(xout, WlT, hbuf, NN, LM, LM, 8,
                                           x, c, Wa, Wc, bl);
    // GEMM2: y1 = h @ W1   [N, 128]
    k_gemm<2><<<391, 256, 0, stream>>>(hbuf, W1T, y1, NN, HC, LM, 1,
                                       nullptr, nullptr, nullptr, nullptr, nullptr);
    // conv1 aggregation + bias + relu
    k_agg1<<<12500, 256, 0, stream>>>(y1, rowptr, csrc, csw, dis, b1, h1);
    // GEMM3: y3 = h1 @ W3   [N, 64]
    k_gemm3<<<12500, 256, 0, stream>>>(h1, W3, y3);
    // conv3 aggregation + bias -> out
    k_agg3<<<12500, 256, 0, stream>>>(y3, rowptr, csrc, csw, dis, b3, outp);
}

// Round 3
// 720.258 us; speedup vs baseline: 1.1961x; 1.1122x over previous
//
#include <hip/hip_runtime.h>
#include <hip/hip_bf16.h>

typedef unsigned short u16;
typedef __attribute__((ext_vector_type(8))) short bf16x8;
typedef __attribute__((ext_vector_type(4))) float f32x4;

constexpr int NN = 50000;   // nodes
constexpr int NE = 800000;  // edges
constexpr int LM = 1024;
constexpr int HC = 128;
constexpr int OC = 64;

// ---- workspace layout (bytes, all 256-aligned) ----
constexpr size_t OFF_ROWPTR = 0;          // (NN+1) int
constexpr size_t OFF_CURSOR = 200192;     // NN int
constexpr size_t OFF_COUNTS = 400384;     // NN int
constexpr size_t OFF_INCL   = 600576;     // NN int
constexpr size_t OFF_BSUM   = 800768;     // 64 int
constexpr size_t OFF_BOFF   = 801024;     // 64 int
constexpr size_t OFF_DIS    = 801280;     // NN float
constexpr size_t OFF_CSRC   = 1001472;    // NE int
constexpr size_t OFF_CSW    = 4201472;    // NE float
constexpr size_t OFF_WLT    = 7401472;    // LM*LM u16
constexpr size_t OFF_W1T    = 9498624;    // HC*LM u16
constexpr size_t OFF_H      = 9760768;    // NN*LM u16
constexpr size_t OFF_Y1     = 112160768;  // NN*HC u16
constexpr size_t OFF_H1     = 124960768;  // NN*HC u16
constexpr size_t OFF_Y3     = 137760768;  // NN*OC u16
// total = 144160768 bytes (~137.5 MB)

__device__ __forceinline__ u16 f2bf(float f) {
    union { float f; unsigned int u; } a; a.f = f;
    unsigned int u = a.u + 0x7FFFu + ((a.u >> 16) & 1u);  // RNE
    return (u16)(u >> 16);
}
__device__ __forceinline__ float bf2f(u16 v) {
    union { unsigned int u; float f; } a; a.u = ((unsigned int)v) << 16;
    return a.f;
}
__device__ __forceinline__ ushort2 pkbf(float a, float b) {
    union { __hip_bfloat162 h; ushort2 u; } cv;
    cv.h = __float22bfloat162_rn(make_float2(a, b));
    return cv.u;
}
__device__ __forceinline__ void async_copy16(u16* lds, const u16* g) {
    __builtin_amdgcn_global_load_lds(
        (const __attribute__((address_space(1))) void*)g,
        (__attribute__((address_space(3))) void*)lds, 16, 0, 0);
}

// ================= CSR build =================
__global__ void k_zero(int* counts) {
    int i = blockIdx.x * 256 + threadIdx.x;
    if (i < NN) counts[i] = 0;
}
__global__ void k_count(const int* __restrict__ ei, int* __restrict__ counts) {
    int e = blockIdx.x * 256 + threadIdx.x;
    if (e < NE) atomicAdd(&counts[ei[NE + e]], 1);
}
__global__ void k_scan1(const int* __restrict__ counts, int* __restrict__ incl,
                        int* __restrict__ bsum) {
    __shared__ int sm[1024];
    int t = threadIdx.x, idx = blockIdx.x * 1024 + t;
    int v = (idx < NN) ? counts[idx] : 0;
    sm[t] = v; __syncthreads();
    for (int off = 1; off < 1024; off <<= 1) {
        int add = (t >= off) ? sm[t - off] : 0;
        __syncthreads();
        sm[t] += add;
        __syncthreads();
    }
    if (idx < NN) incl[idx] = sm[t];
    if (t == 1023) bsum[blockIdx.x] = sm[t];
}
__global__ void k_scan2(const int* __restrict__ bsum, int* __restrict__ boff, int nb) {
    if (threadIdx.x == 0 && blockIdx.x == 0) {
        int run = 0;
        for (int i = 0; i < nb; i++) { boff[i] = run; run += bsum[i]; }
    }
}
__global__ void k_scan3(const int* __restrict__ incl, const int* __restrict__ counts,
                        const int* __restrict__ boff, int* __restrict__ rowptr,
                        int* __restrict__ cursor) {
    int idx = blockIdx.x * 256 + threadIdx.x;
    if (idx < NN) {
        int rp = incl[idx] - counts[idx] + boff[idx >> 10];
        rowptr[idx] = rp;
        cursor[idx] = rp;
    } else if (idx == NN) {
        rowptr[NN] = NE;
    }
}
__global__ void k_fill(const int* __restrict__ ei, const float* __restrict__ ew,
                       int* __restrict__ cursor, int* __restrict__ csrc,
                       float* __restrict__ csw) {
    int e = blockIdx.x * 256 + threadIdx.x;
    if (e < NE) {
        int d = ei[NE + e];
        int slot = atomicAdd(&cursor[d], 1);
        csrc[slot] = ei[e];
        csw[slot] = ew[e];
    }
}
__global__ void k_deg(const int* __restrict__ rowptr, const float* __restrict__ csw,
                      float* __restrict__ dis) {
    int i = blockIdx.x * 256 + threadIdx.x;
    if (i >= NN) return;
    float d = 1.0f;  // self loop weight
    int p1 = rowptr[i + 1];
    for (int p = rowptr[i]; p < p1; ++p) d += csw[p];
    dis[i] = rsqrtf(d);
}
// fold dis[src] into edge weight (in-place; each p read-then-write own elem)
__global__ void k_wnorm(const int* __restrict__ csrc, float* __restrict__ csw,
                        const float* __restrict__ dis) {
    int p = blockIdx.x * 256 + threadIdx.x;
    if (p < NE) csw[p] = csw[p] * dis[csrc[p]];
}

// ================= weight conversion =================
__global__ void k_cvtWl(const float* __restrict__ Wl, u16* __restrict__ WlT) {
    __shared__ float sm[32][33];
    int k0 = blockIdx.y * 32, n0 = blockIdx.x * 32;
    sm[threadIdx.y][threadIdx.x] = Wl[(size_t)(k0 + threadIdx.y) * LM + n0 + threadIdx.x];
    __syncthreads();
    WlT[(size_t)(n0 + threadIdx.y) * LM + k0 + threadIdx.x] = f2bf(sm[threadIdx.x][threadIdx.y]);
}
__global__ void k_cvtW1(const float* __restrict__ W1, u16* __restrict__ W1T) {
    int idx = blockIdx.x * 256 + threadIdx.x;  // HC*LM, output-major
    if (idx >= HC * LM) return;
    int o = idx >> 10, k = idx & 1023;
    W1T[idx] = f2bf(W1[(size_t)k * HC + o]);
}

// ================= MFMA GEMM (128x128 tile, BK=64, XOR-swizzled LDS) =================
// LDS tile layout: 16B chunk (row rl, k-chunk k8) at chunk slot rl*8+(k8^(rl&7)).
// [R1: conflicts 3.8e7 -> 0 measured]
// MODE 1: A fp32. R2: software-pipelined — tile k+1's global loads are issued
// AFTER the staging barrier, so compute(k)'s MFMA+ds_read (~300+ cyc) hides
// their latency; the next iteration's barrier drain finds them complete.
// MODE 2: A bf16 via async global_load_lds (fire-and-forget, m97-style).
template <int MODE>
__global__ __launch_bounds__(256, 2) void k_gemm(
    const void* __restrict__ Aptr, const u16* __restrict__ Bt, u16* __restrict__ Cout,
    int M, int Nn, int K, int nby,
    const float* __restrict__ xv, const float* __restrict__ cv,
    const float* __restrict__ Wa, const float* __restrict__ Wc,
    const float* __restrict__ bl) {
    __shared__ u16 lA[128 * 64];
    __shared__ u16 lB[128 * 64];
    const int tid = threadIdx.x;
    const int lane = tid & 63, wv = tid >> 6;
    const int mtiles = (M + 127) >> 7;
    int bx, by;
    if (nby > 1) {
        int x = blockIdx.x & 7, j = blockIdx.x >> 3;
        bx = (j & ~7) | x;
        by = j & 7;
        if (bx >= mtiles) return;  // uniform across block, before any barrier
    } else {
        bx = blockIdx.x; by = 0;
    }
    const int m0 = bx * 128, n0 = by * 128;
    const int wm = (wv >> 1) * 64, wn = (wv & 1) * 64;
    const int fr = lane & 15, qd = lane >> 4;
    const int nt = K >> 6;

    f32x4 acc[4][4] = {};
    const float* A32 = (const float*)Aptr;

    // per-thread staging coords (MODE 1): 4 chunks of 16B (=8 fp32 -> 8 bf16)
    int srl[4], sslot[4]; const float* sbase[4];
    float4 pf[8];
    if constexpr (MODE == 1) {
        #pragma unroll
        for (int i = 0; i < 4; i++) {
            int cidx = i * 256 + tid;
            srl[i] = cidx >> 3; sslot[i] = cidx & 7;
            int k8 = sslot[i] ^ (srl[i] & 7);
            int row = m0 + srl[i]; if (row >= M) row = M - 1;
            sbase[i] = A32 + (size_t)row * K + k8 * 8;
        }
        #pragma unroll
        for (int i = 0; i < 4; i++) {           // prefetch tile 0
            pf[2 * i]     = *(const float4*)(sbase[i]);
            pf[2 * i + 1] = *(const float4*)(sbase[i] + 4);
        }
    }

    for (int kt = 0; kt < nt; kt++) {
        const int k0 = kt << 6;
        __syncthreads();   // previous compute done reading LDS
        // stage B^T tile via async direct-to-LDS, XOR swizzle
        #pragma unroll
        for (int i = 0; i < 4; i++) {
            int r0 = i * 32 + wv * 8;
            int rl = r0 + (lane >> 3);
            int slot = lane & 7;
            int k8 = slot ^ (rl & 7);
            int col = n0 + rl; if (col >= Nn) col = Nn - 1;
            const u16* g = Bt + (size_t)col * K + k0 + k8 * 8;
            async_copy16(&lB[r0 * 64], g);
        }
        if constexpr (MODE == 2) {
            #pragma unroll
            for (int i = 0; i < 4; i++) {
                int r0 = i * 32 + wv * 8;
                int rl = r0 + (lane >> 3);
                int slot = lane & 7;
                int k8 = slot ^ (rl & 7);
                int row = m0 + rl; if (row >= M) row = M - 1;
                const u16* g = (const u16*)Aptr + (size_t)row * K + k0 + k8 * 8;
                async_copy16(&lA[r0 * 64], g);
            }
        } else {
            // convert prefetched regs (tile kt) -> LDS
            #pragma unroll
            for (int i = 0; i < 4; i++) {
                union { ushort2 u2[4]; bf16x8 v; } pk;
                pk.u2[0] = pkbf(pf[2 * i].x, pf[2 * i].y);
                pk.u2[1] = pkbf(pf[2 * i].z, pf[2 * i].w);
                pk.u2[2] = pkbf(pf[2 * i + 1].x, pf[2 * i + 1].y);
                pk.u2[3] = pkbf(pf[2 * i + 1].z, pf[2 * i + 1].w);
                *(bf16x8*)&lA[srl[i] * 64 + sslot[i] * 8] = pk.v;
            }
        }
        __syncthreads();   // staging visible
        if constexpr (MODE == 1) {
            if (kt + 1 < nt) {  // issue tile kt+1 loads; compute hides latency
                #pragma unroll
                for (int i = 0; i < 4; i++) {
                    pf[2 * i]     = *(const float4*)(sbase[i] + k0 + 64);
                    pf[2 * i + 1] = *(const float4*)(sbase[i] + k0 + 68);
                }
            }
        }
        #pragma unroll
        for (int s = 0; s < 2; s++) {
            const int slot = (s * 4 + qd) ^ (fr & 7);  // same for A and B frags
            bf16x8 af[4], bfm[4];
            #pragma unroll
            for (int mi = 0; mi < 4; mi++)
                af[mi] = *(const bf16x8*)&lA[(wm + mi * 16 + fr) * 64 + slot * 8];
            #pragma unroll
            for (int ni = 0; ni < 4; ni++)
                bfm[ni] = *(const bf16x8*)&lB[(wn + ni * 16 + fr) * 64 + slot * 8];
            #pragma unroll
            for (int mi = 0; mi < 4; mi++)
                #pragma unroll
                for (int ni = 0; ni < 4; ni++)
                    acc[mi][ni] = __builtin_amdgcn_mfma_f32_16x16x32_bf16(
                        af[mi], bfm[ni], acc[mi][ni], 0, 0, 0);
        }
    }

    // epilogue: C/D layout col=lane&15, row=(lane>>4)*4+reg
    int jj[4]; float waj[4], wcj[4], blj[4];
    #pragma unroll
    for (int ni = 0; ni < 4; ni++) {
        jj[ni] = n0 + wn + ni * 16 + fr;
        if constexpr (MODE == 1) { waj[ni] = Wa[jj[ni]]; wcj[ni] = Wc[jj[ni]]; blj[ni] = bl[jj[ni]]; }
    }
    #pragma unroll
    for (int mi = 0; mi < 4; mi++) {
        #pragma unroll
        for (int r = 0; r < 4; r++) {
            int row = m0 + wm + mi * 16 + qd * 4 + r;
            if (row < M) {
                float xb = 0.f, cb = 0.f;
                if constexpr (MODE == 1) { xb = xv[row]; cb = cv[row]; }
                #pragma unroll
                for (int ni = 0; ni < 4; ni++) {
                    float v = acc[mi][ni][r];
                    if constexpr (MODE == 1) {
                        v += xb * waj[ni] + cb * wcj[ni] + blj[ni];
                        v = fmaxf(v, 0.f);
                    }
                    Cout[(size_t)row * Nn + jj[ni]] = f2bf(v);
                }
            }
        }
    }
}

// ================= aggregation 1: h1 = relu(Anorm @ y1 + b1), HC=128 =================
// csw already holds dis[src]*w; di factored out of the edge loop.
__global__ __launch_bounds__(256) void k_agg1(
    const u16* __restrict__ y1, const int* __restrict__ rowptr,
    const int* __restrict__ csrc, const float* __restrict__ csw,
    const float* __restrict__ dis, const float* __restrict__ b1,
    u16* __restrict__ h1) {
    int node = blockIdx.x * 4 + (threadIdx.x >> 6);
    int lane = threadIdx.x & 63;
    if (node >= NN) return;
    float di = dis[node];
    int p0 = rowptr[node], p1 = rowptr[node + 1];
    ushort2 sv = *(const ushort2*)(y1 + (size_t)node * HC + lane * 2);
    float a0 = di * bf2f(sv.x), a1 = di * bf2f(sv.y);
    #pragma unroll 4
    for (int p = p0; p < p1; ++p) {
        int s = csrc[p];
        float nm = csw[p];
        ushort2 v = *(const ushort2*)(y1 + (size_t)s * HC + lane * 2);
        a0 += nm * bf2f(v.x);
        a1 += nm * bf2f(v.y);
    }
    a0 = fmaxf(di * a0 + b1[lane * 2], 0.f);
    a1 = fmaxf(di * a1 + b1[lane * 2 + 1], 0.f);
    ushort2 r; r.x = f2bf(a0); r.y = f2bf(a1);
    *(ushort2*)(h1 + (size_t)node * HC + lane * 2) = r;
}

// ================= GEMM3: y3 = h1 @ W3 (K=128 -> 64), vector ALU =================
__global__ __launch_bounds__(256) void k_gemm3(
    const u16* __restrict__ h1, const float* __restrict__ W3, u16* __restrict__ y3) {
    int node = blockIdx.x * 4 + (threadIdx.x >> 6);
    int o = threadIdx.x & 63;
    if (node >= NN) return;
    const u16* hrow = h1 + (size_t)node * HC;
    float acc = 0.f;
    #pragma unroll 16
    for (int k = 0; k < HC; ++k)
        acc += bf2f(hrow[k]) * W3[(size_t)k * OC + o];
    y3[(size_t)node * OC + o] = f2bf(acc);
}

// ================= aggregation 3: out = Anorm @ y3 + b3, OC=64 =================
__global__ __launch_bounds__(256) void k_agg3(
    const u16* __restrict__ y3, const int* __restrict__ rowptr,
    const int* __restrict__ csrc, const float* __restrict__ csw,
    const float* __restrict__ dis, const float* __restrict__ b3,
    float* __restrict__ outp) {
    int node = blockIdx.x * 4 + (threadIdx.x >> 6);
    int lane = threadIdx.x & 63;
    if (node >= NN) return;
    float di = dis[node];
    int p0 = rowptr[node], p1 = rowptr[node + 1];
    float a = di * bf2f(y3[(size_t)node * OC + lane]);
    #pragma unroll 4
    for (int p = p0; p < p1; ++p) {
        int s = csrc[p];
        a += csw[p] * bf2f(y3[(size_t)s * OC + lane]);
    }
    outp[(size_t)node * OC + lane] = di * a + b3[lane];
}

extern "C" void kernel_launch(void* const* d_in, const int* in_sizes, int n_in,
                              void* d_out, int out_size, void* d_ws, size_t ws_size,
                              hipStream_t stream) {
    const float* x    = (const float*)d_in[0];
    const float* xout = (const float*)d_in[1];
    const float* c    = (const float*)d_in[2];
    const int*   ei   = (const int*)d_in[3];
    const float* ew   = (const float*)d_in[4];
    const float* Wa   = (const float*)d_in[5];
    const float* Wc   = (const float*)d_in[6];
    const float* Wl   = (const float*)d_in[7];
    const float* bl   = (const float*)d_in[8];
    const float* W1   = (const float*)d_in[9];
    const float* b1   = (const float*)d_in[10];
    const float* W3   = (const float*)d_in[11];
    const float* b3   = (const float*)d_in[12];
    float* outp = (float*)d_out;

    char* ws = (char*)d_ws;
    int*   rowptr = (int*)(ws + OFF_ROWPTR);
    int*   cursor = (int*)(ws + OFF_CURSOR);
    int*   counts = (int*)(ws + OFF_COUNTS);
    int*   incl   = (int*)(ws + OFF_INCL);
    int*   bsum   = (int*)(ws + OFF_BSUM);
    int*   boff   = (int*)(ws + OFF_BOFF);
    float* dis    = (float*)(ws + OFF_DIS);
    int*   csrc   = (int*)(ws + OFF_CSRC);
    float* csw    = (float*)(ws + OFF_CSW);
    u16*   WlT    = (u16*)(ws + OFF_WLT);
    u16*   W1T    = (u16*)(ws + OFF_W1T);
    u16*   hbuf   = (u16*)(ws + OFF_H);
    u16*   y1     = (u16*)(ws + OFF_Y1);
    u16*   h1     = (u16*)(ws + OFF_H1);
    u16*   y3     = (u16*)(ws + OFF_Y3);

    // CSR build
    k_zero <<<196, 256, 0, stream>>>(counts);
    k_count<<<3125, 256, 0, stream>>>(ei, counts);
    k_scan1<<<49, 1024, 0, stream>>>(counts, incl, bsum);
    k_scan2<<<1, 64, 0, stream>>>(bsum, boff, 49);
    k_scan3<<<196, 256, 0, stream>>>(incl, counts, boff, rowptr, cursor);
    k_fill <<<3125, 256, 0, stream>>>(ei, ew, cursor, csrc, csw);
    k_deg  <<<196, 256, 0, stream>>>(rowptr, csw, dis);
    k_wnorm<<<3125, 256, 0, stream>>>(csrc, csw, dis);

    // weight conversion (bf16, transposed to [out, K])
    k_cvtWl<<<dim3(32, 32), dim3(32, 32), 0, stream>>>(Wl, WlT);
    k_cvtW1<<<512, 256, 0, stream>>>(W1, W1T);

    // GEMM1: h = relu(x_out@Wl + x*Wa + c*Wc + bl)   [N, 1024]
    k_gemm<1><<<392 * 8, 256, 0, stream>>>(xout, WlT, hbuf, NN, LM, LM, 8,
                                           x, c, Wa, Wc, bl);
    // GEMM2: y1 = h @ W1   [N, 128]
    k_gemm<2><<<391, 256, 0, stream>>>(hbuf, W1T, y1, NN, HC, LM, 1,
                                       nullptr, nullptr, nullptr, nullptr, nullptr);
    // conv1 aggregation + bias + relu
    k_agg1<<<12500, 256, 0, stream>>>(y1, rowptr, csrc, csw, dis, b1, h1);
    // GEMM3: y3 = h1 @ W3   [N, 64]
    k_gemm3<<<12500, 256, 0, stream>>>(h1, W3, y3);
    // conv3 aggregation + bias -> out
    k_agg3<<<12500, 256, 0, stream>>>(y3, rowptr, csrc, csw, dis, b3, outp);
}

// Round 4
// 714.340 us; speedup vs baseline: 1.2060x; 1.0083x over previous
//
#include <hip/hip_runtime.h>
#include <hip/hip_bf16.h>

typedef unsigned short u16;
typedef __attribute__((ext_vector_type(8))) short bf16x8;
typedef __attribute__((ext_vector_type(4))) float f32x4;

constexpr int NN = 50000;   // nodes
constexpr int NE = 800000;  // edges
constexpr int LM = 1024;
constexpr int HC = 128;
constexpr int OC = 64;

// ---- workspace layout (bytes, all 256-aligned) ----
constexpr size_t OFF_ROWPTR = 0;          // (NN+1) int
constexpr size_t OFF_CURSOR = 200192;     // NN int
constexpr size_t OFF_COUNTS = 400384;     // NN int
constexpr size_t OFF_INCL   = 600576;     // NN int
constexpr size_t OFF_BSUM   = 800768;     // 64 int
constexpr size_t OFF_BOFF   = 801024;     // 64 int
constexpr size_t OFF_DIS    = 801280;     // NN float
constexpr size_t OFF_META   = 1001472;    // NE int2 (src, w-bits) = 6.4 MB
constexpr size_t OFF_WLT    = 7401472;    // LM*LM u16
constexpr size_t OFF_W1T    = 9498624;    // HC*LM u16
constexpr size_t OFF_H      = 9760768;    // NN*LM u16
constexpr size_t OFF_Y1     = 112160768;  // NN*HC u16
constexpr size_t OFF_DEGF   = 124960768;  // NN float (reuses old h1 slot)
constexpr size_t OFF_Y3     = 137760768;  // NN*OC u16
// total = 144160768 bytes (~137.5 MB)

__device__ __forceinline__ u16 f2bf(float f) {
    union { float f; unsigned int u; } a; a.f = f;
    unsigned int u = a.u + 0x7FFFu + ((a.u >> 16) & 1u);  // RNE
    return (u16)(u >> 16);
}
__device__ __forceinline__ float bf2f(u16 v) {
    union { unsigned int u; float f; } a; a.u = ((unsigned int)v) << 16;
    return a.f;
}
__device__ __forceinline__ ushort2 pkbf(float a, float b) {
    union { __hip_bfloat162 h; ushort2 u; } cv;
    cv.h = __float22bfloat162_rn(make_float2(a, b));
    return cv.u;
}
__device__ __forceinline__ void async_copy16(u16* lds, const u16* g) {
    __builtin_amdgcn_global_load_lds(
        (const __attribute__((address_space(1))) void*)g,
        (__attribute__((address_space(3))) void*)lds, 16, 0, 0);
}

// ================= fused setup: zero counts/degf + cvt Wl + cvt W1 =========
// blocks [0,196): zero; [196,1220): Wl transpose+cvt; [1220,1732): W1 cvt
__global__ void k_setup(int* __restrict__ counts, float* __restrict__ degf,
                        const float* __restrict__ Wl, u16* __restrict__ WlT,
                        const float* __restrict__ W1, u16* __restrict__ W1T) {
    int b = blockIdx.x, t = threadIdx.x;
    if (b < 196) {
        int i = b * 256 + t;
        if (i < NN) { counts[i] = 0; degf[i] = 0.f; }
    } else if (b < 196 + 1024) {
        __shared__ float sm[32][33];
        int bb = b - 196;
        int n0 = (bb & 31) * 32, k0 = (bb >> 5) * 32;
        int ty = t >> 5, tx = t & 31;
        #pragma unroll
        for (int i = 0; i < 4; i++)
            sm[ty + i * 8][tx] = Wl[(size_t)(k0 + ty + i * 8) * LM + n0 + tx];
        __syncthreads();
        #pragma unroll
        for (int i = 0; i < 4; i++)
            WlT[(size_t)(n0 + ty + i * 8) * LM + k0 + tx] = f2bf(sm[tx][ty + i * 8]);
    } else {
        int idx = (b - 1220) * 256 + t;  // HC*LM, output-major
        if (idx < HC * LM) {
            int o = idx >> 10, k = idx & 1023;
            W1T[idx] = f2bf(W1[(size_t)k * HC + o]);
        }
    }
}

// ================= CSR build =================
__global__ void k_count(const int* __restrict__ ei, const float* __restrict__ ew,
                        int* __restrict__ counts, float* __restrict__ degf) {
    int e = blockIdx.x * 256 + threadIdx.x;
    if (e < NE) {
        int d = ei[NE + e];
        atomicAdd(&counts[d], 1);
        atomicAdd(&degf[d], ew[e]);
    }
}
__global__ void k_scan1(const int* __restrict__ counts, int* __restrict__ incl,
                        int* __restrict__ bsum) {
    __shared__ int sm[1024];
    int t = threadIdx.x, idx = blockIdx.x * 1024 + t;
    int v = (idx < NN) ? counts[idx] : 0;
    sm[t] = v; __syncthreads();
    for (int off = 1; off < 1024; off <<= 1) {
        int add = (t >= off) ? sm[t - off] : 0;
        __syncthreads();
        sm[t] += add;
        __syncthreads();
    }
    if (idx < NN) incl[idx] = sm[t];
    if (t == 1023) bsum[blockIdx.x] = sm[t];
}
__global__ void k_scan2(const int* __restrict__ bsum, int* __restrict__ boff, int nb) {
    if (threadIdx.x == 0 && blockIdx.x == 0) {
        int run = 0;
        for (int i = 0; i < nb; i++) { boff[i] = run; run += bsum[i]; }
    }
}
// also computes dis = rsqrt(1 + weighted in-degree)
__global__ void k_scan3(const int* __restrict__ incl, const int* __restrict__ counts,
                        const int* __restrict__ boff, const float* __restrict__ degf,
                        int* __restrict__ rowptr, int* __restrict__ cursor,
                        float* __restrict__ dis) {
    int idx = blockIdx.x * 256 + threadIdx.x;
    if (idx < NN) {
        int rp = incl[idx] - counts[idx] + boff[idx >> 10];
        rowptr[idx] = rp;
        cursor[idx] = rp;
        dis[idx] = rsqrtf(1.0f + degf[idx]);
    } else if (idx == NN) {
        rowptr[NN] = NE;
    }
}
__global__ void k_fill(const int* __restrict__ ei, const float* __restrict__ ew,
                       int* __restrict__ cursor, int2* __restrict__ meta) {
    int e = blockIdx.x * 256 + threadIdx.x;
    if (e < NE) {
        int d = ei[NE + e];
        int slot = atomicAdd(&cursor[d], 1);
        meta[slot] = make_int2(ei[e], __float_as_int(ew[e]));
    }
}
// fold dis[src] into edge weight (in-place)
__global__ void k_wnorm(int2* __restrict__ meta, const float* __restrict__ dis) {
    int p = blockIdx.x * 256 + threadIdx.x;
    if (p < NE) {
        int2 m = meta[p];
        meta[p].y = __float_as_int(__int_as_float(m.y) * dis[m.x]);
    }
}

// ================= MFMA GEMM (128x128 tile, BK=64, XOR-swizzled LDS) =================
// LDS tile layout: 16B chunk (row rl, k-chunk k8) at chunk slot rl*8+(k8^(rl&7)).
// [R1: conflicts 3.8e7 -> 0 measured]
// MODE 1: A fp32, reg-prefetch pipeline; epilogue relu(acc + x*Wa + c*Wc + bl)
// MODE 2: A bf16 via async global_load_lds (fire-and-forget, m97-style).
template <int MODE>
__global__ __launch_bounds__(256, 2) void k_gemm(
    const void* __restrict__ Aptr, const u16* __restrict__ Bt, u16* __restrict__ Cout,
    int M, int Nn, int K, int nby,
    const float* __restrict__ xv, const float* __restrict__ cv,
    const float* __restrict__ Wa, const float* __restrict__ Wc,
    const float* __restrict__ bl) {
    __shared__ u16 lA[128 * 64];
    __shared__ u16 lB[128 * 64];
    const int tid = threadIdx.x;
    const int lane = tid & 63, wv = tid >> 6;
    const int mtiles = (M + 127) >> 7;
    int bx, by;
    if (nby > 1) {
        int x = blockIdx.x & 7, j = blockIdx.x >> 3;
        bx = (j & ~7) | x;
        by = j & 7;
        if (bx >= mtiles) return;  // uniform across block, before any barrier
    } else {
        bx = blockIdx.x; by = 0;
    }
    const int m0 = bx * 128, n0 = by * 128;
    const int wm = (wv >> 1) * 64, wn = (wv & 1) * 64;
    const int fr = lane & 15, qd = lane >> 4;
    const int nt = K >> 6;

    f32x4 acc[4][4] = {};
    const float* A32 = (const float*)Aptr;

    // per-thread staging coords (MODE 1): 4 chunks of 16B (=8 fp32 -> 8 bf16)
    int srl[4], sslot[4]; const float* sbase[4];
    float4 pf[8];
    if constexpr (MODE == 1) {
        #pragma unroll
        for (int i = 0; i < 4; i++) {
            int cidx = i * 256 + tid;
            srl[i] = cidx >> 3; sslot[i] = cidx & 7;
            int k8 = sslot[i] ^ (srl[i] & 7);
            int row = m0 + srl[i]; if (row >= M) row = M - 1;
            sbase[i] = A32 + (size_t)row * K + k8 * 8;
        }
        #pragma unroll
        for (int i = 0; i < 4; i++) {           // prefetch tile 0
            pf[2 * i]     = *(const float4*)(sbase[i]);
            pf[2 * i + 1] = *(const float4*)(sbase[i] + 4);
        }
    }

    for (int kt = 0; kt < nt; kt++) {
        const int k0 = kt << 6;
        __syncthreads();   // previous compute done reading LDS
        // stage B^T tile via async direct-to-LDS, XOR swizzle
        #pragma unroll
        for (int i = 0; i < 4; i++) {
            int r0 = i * 32 + wv * 8;
            int rl = r0 + (lane >> 3);
            int slot = lane & 7;
            int k8 = slot ^ (rl & 7);
            int col = n0 + rl; if (col >= Nn) col = Nn - 1;
            const u16* g = Bt + (size_t)col * K + k0 + k8 * 8;
            async_copy16(&lB[r0 * 64], g);
        }
        if constexpr (MODE == 2) {
            #pragma unroll
            for (int i = 0; i < 4; i++) {
                int r0 = i * 32 + wv * 8;
                int rl = r0 + (lane >> 3);
                int slot = lane & 7;
                int k8 = slot ^ (rl & 7);
                int row = m0 + rl; if (row >= M) row = M - 1;
                const u16* g = (const u16*)Aptr + (size_t)row * K + k0 + k8 * 8;
                async_copy16(&lA[r0 * 64], g);
            }
        } else {
            // convert prefetched regs (tile kt) -> LDS
            #pragma unroll
            for (int i = 0; i < 4; i++) {
                union { ushort2 u2[4]; bf16x8 v; } pk;
                pk.u2[0] = pkbf(pf[2 * i].x, pf[2 * i].y);
                pk.u2[1] = pkbf(pf[2 * i].z, pf[2 * i].w);
                pk.u2[2] = pkbf(pf[2 * i + 1].x, pf[2 * i + 1].y);
                pk.u2[3] = pkbf(pf[2 * i + 1].z, pf[2 * i + 1].w);
                *(bf16x8*)&lA[srl[i] * 64 + sslot[i] * 8] = pk.v;
            }
        }
        __syncthreads();   // staging visible
        if constexpr (MODE == 1) {
            if (kt + 1 < nt) {  // issue tile kt+1 loads; compute hides latency
                #pragma unroll
                for (int i = 0; i < 4; i++) {
                    pf[2 * i]     = *(const float4*)(sbase[i] + k0 + 64);
                    pf[2 * i + 1] = *(const float4*)(sbase[i] + k0 + 68);
                }
            }
        }
        #pragma unroll
        for (int s = 0; s < 2; s++) {
            const int slot = (s * 4 + qd) ^ (fr & 7);  // same for A and B frags
            bf16x8 af[4], bfm[4];
            #pragma unroll
            for (int mi = 0; mi < 4; mi++)
                af[mi] = *(const bf16x8*)&lA[(wm + mi * 16 + fr) * 64 + slot * 8];
            #pragma unroll
            for (int ni = 0; ni < 4; ni++)
                bfm[ni] = *(const bf16x8*)&lB[(wn + ni * 16 + fr) * 64 + slot * 8];
            #pragma unroll
            for (int mi = 0; mi < 4; mi++)
                #pragma unroll
                for (int ni = 0; ni < 4; ni++)
                    acc[mi][ni] = __builtin_amdgcn_mfma_f32_16x16x32_bf16(
                        af[mi], bfm[ni], acc[mi][ni], 0, 0, 0);
        }
    }

    // epilogue: C/D layout col=lane&15, row=(lane>>4)*4+reg
    int jj[4]; float waj[4], wcj[4], blj[4];
    #pragma unroll
    for (int ni = 0; ni < 4; ni++) {
        jj[ni] = n0 + wn + ni * 16 + fr;
        if constexpr (MODE == 1) { waj[ni] = Wa[jj[ni]]; wcj[ni] = Wc[jj[ni]]; blj[ni] = bl[jj[ni]]; }
    }
    #pragma unroll
    for (int mi = 0; mi < 4; mi++) {
        #pragma unroll
        for (int r = 0; r < 4; r++) {
            int row = m0 + wm + mi * 16 + qd * 4 + r;
            if (row < M) {
                float xb = 0.f, cb = 0.f;
                if constexpr (MODE == 1) { xb = xv[row]; cb = cv[row]; }
                #pragma unroll
                for (int ni = 0; ni < 4; ni++) {
                    float v = acc[mi][ni][r];
                    if constexpr (MODE == 1) {
                        v += xb * waj[ni] + cb * wcj[ni] + blj[ni];
                        v = fmaxf(v, 0.f);
                    }
                    Cout[(size_t)row * Nn + jj[ni]] = f2bf(v);
                }
            }
        }
    }
}

// ====== fused agg1 + gemm3: per node, h1 = relu(Anorm@y1 + b1); y3 = h1@W3 ======
// 512 threads = 8 waves = 8 nodes/block. h1 row staged in LDS (wave-private,
// no barrier needed); W3 read from global (L1-resident 32 KB, 256B/row coalesced).
__global__ __launch_bounds__(512) void k_agg1g3(
    const u16* __restrict__ y1, const int* __restrict__ rowptr,
    const int2* __restrict__ meta, const float* __restrict__ dis,
    const float* __restrict__ b1, const float* __restrict__ W3,
    u16* __restrict__ y3) {
    __shared__ float hrow[8][HC];
    int wv = threadIdx.x >> 6, lane = threadIdx.x & 63;
    int node = blockIdx.x * 8 + wv;
    if (node >= NN) return;
    float di = dis[node];
    int p0 = rowptr[node], p1 = rowptr[node + 1];
    ushort2 sv = *(const ushort2*)(y1 + (size_t)node * HC + lane * 2);
    float a0 = di * bf2f(sv.x), a1 = di * bf2f(sv.y);
    #pragma unroll 8
    for (int p = p0; p < p1; ++p) {
        int2 m = meta[p];
        float nm = __int_as_float(m.y);
        ushort2 v = *(const ushort2*)(y1 + (size_t)m.x * HC + lane * 2);
        a0 += nm * bf2f(v.x);
        a1 += nm * bf2f(v.y);
    }
    a0 = fmaxf(di * a0 + b1[lane * 2], 0.f);
    a1 = fmaxf(di * a1 + b1[lane * 2 + 1], 0.f);
    hrow[wv][lane * 2] = a0;
    hrow[wv][lane * 2 + 1] = a1;
    // wave-synchronous: LDS write->read within the same wave needs no barrier
    float acc = 0.f;
    #pragma unroll 8
    for (int k = 0; k < HC; ++k)
        acc += hrow[wv][k] * W3[(size_t)k * OC + lane];
    y3[(size_t)node * OC + lane] = f2bf(acc);
}

// ================= aggregation 3: out = Anorm @ y3 + b3, OC=64 =================
__global__ __launch_bounds__(256) void k_agg3(
    const u16* __restrict__ y3, const int* __restrict__ rowptr,
    const int2* __restrict__ meta, const float* __restrict__ dis,
    const float* __restrict__ b3, float* __restrict__ outp) {
    int node = blockIdx.x * 4 + (threadIdx.x >> 6);
    int lane = threadIdx.x & 63;
    if (node >= NN) return;
    float di = dis[node];
    int p0 = rowptr[node], p1 = rowptr[node + 1];
    float a = di * bf2f(y3[(size_t)node * OC + lane]);
    #pragma unroll 8
    for (int p = p0; p < p1; ++p) {
        int2 m = meta[p];
        a += __int_as_float(m.y) * bf2f(y3[(size_t)m.x * OC + lane]);
    }
    outp[(size_t)node * OC + lane] = di * a + b3[lane];
}

extern "C" void kernel_launch(void* const* d_in, const int* in_sizes, int n_in,
                              void* d_out, int out_size, void* d_ws, size_t ws_size,
                              hipStream_t stream) {
    const float* x    = (const float*)d_in[0];
    const float* xout = (const float*)d_in[1];
    const float* c    = (const float*)d_in[2];
    const int*   ei   = (const int*)d_in[3];
    const float* ew   = (const float*)d_in[4];
    const float* Wa   = (const float*)d_in[5];
    const float* Wc   = (const float*)d_in[6];
    const float* Wl   = (const float*)d_in[7];
    const float* bl   = (const float*)d_in[8];
    const float* W1   = (const float*)d_in[9];
    const float* b1   = (const float*)d_in[10];
    const float* W3   = (const float*)d_in[11];
    const float* b3   = (const float*)d_in[12];
    float* outp = (float*)d_out;

    char* ws = (char*)d_ws;
    int*   rowptr = (int*)(ws + OFF_ROWPTR);
    int*   cursor = (int*)(ws + OFF_CURSOR);
    int*   counts = (int*)(ws + OFF_COUNTS);
    int*   incl   = (int*)(ws + OFF_INCL);
    int*   bsum   = (int*)(ws + OFF_BSUM);
    int*   boff   = (int*)(ws + OFF_BOFF);
    float* dis    = (float*)(ws + OFF_DIS);
    int2*  meta   = (int2*)(ws + OFF_META);
    u16*   WlT    = (u16*)(ws + OFF_WLT);
    u16*   W1T    = (u16*)(ws + OFF_W1T);
    u16*   hbuf   = (u16*)(ws + OFF_H);
    u16*   y1     = (u16*)(ws + OFF_Y1);
    float* degf   = (float*)(ws + OFF_DEGF);
    u16*   y3     = (u16*)(ws + OFF_Y3);

    // setup: zero counts/degf + weight cvt (one kernel)
    k_setup<<<1732, 256, 0, stream>>>(counts, degf, Wl, WlT, W1, W1T);
    // CSR build (deg accumulated by atomics in k_count; dis folded into scan3)
    k_count<<<3125, 256, 0, stream>>>(ei, ew, counts, degf);
    k_scan1<<<49, 1024, 0, stream>>>(counts, incl, bsum);
    k_scan2<<<1, 64, 0, stream>>>(bsum, boff, 49);
    k_scan3<<<196, 256, 0, stream>>>(incl, counts, boff, degf, rowptr, cursor, dis);
    k_fill <<<3125, 256, 0, stream>>>(ei, ew, cursor, meta);
    k_wnorm<<<3125, 256, 0, stream>>>(meta, dis);

    // GEMM1: h = relu(x_out@Wl + x*Wa + c*Wc + bl)   [N, 1024]
    k_gemm<1><<<392 * 8, 256, 0, stream>>>(xout, WlT, hbuf, NN, LM, LM, 8,
                                           x, c, Wa, Wc, bl);
    // GEMM2: y1 = h @ W1   [N, 128]
    k_gemm<2><<<391, 256, 0, stream>>>(hbuf, W1T, y1, NN, HC, LM, 1,
                                       nullptr, nullptr, nullptr, nullptr, nullptr);
    // conv1 aggregation + bias + relu + conv3 linear (fused)
    k_agg1g3<<<6250, 512, 0, stream>>>(y1, rowptr, meta, dis, b1, W3, y3);
    // conv3 aggregation + bias -> out
    k_agg3<<<12500, 256, 0, stream>>>(y3, rowptr, meta, dis, b3, outp);
}

// Round 5
// 707.612 us; speedup vs baseline: 1.2175x; 1.0095x over previous
//
#include <hip/hip_runtime.h>
#include <hip/hip_bf16.h>

typedef unsigned short u16;
typedef __attribute__((ext_vector_type(8))) short bf16x8;
typedef __attribute__((ext_vector_type(4))) float f32x4;

constexpr int NN = 50000;   // nodes
constexpr int NE = 800000;  // edges
constexpr int LM = 1024;
constexpr int HC = 128;
constexpr int OC = 64;

// ---- workspace layout (bytes, all 256-aligned) ----
constexpr size_t OFF_ROWPTR = 0;          // (NN+1) int
constexpr size_t OFF_CURSOR = 200192;     // NN int
constexpr size_t OFF_COUNTS = 400384;     // NN int
constexpr size_t OFF_INCL   = 600576;     // NN int
constexpr size_t OFF_BSUM   = 800768;     // 64 int
constexpr size_t OFF_BOFF   = 801024;     // 64 int
constexpr size_t OFF_DIS    = 801280;     // NN float
constexpr size_t OFF_META   = 1001472;    // NE int2 (src, w-bits) = 6.4 MB
constexpr size_t OFF_WLT    = 7401472;    // LM*LM u16
constexpr size_t OFF_W1T    = 9498624;    // HC*LM u16
constexpr size_t OFF_H      = 9760768;    // NN*LM u16
constexpr size_t OFF_Y1     = 112160768;  // NN*HC u16
constexpr size_t OFF_DEGF   = 124960768;  // NN float
constexpr size_t OFF_Y3     = 137760768;  // NN*OC u16

__device__ __forceinline__ u16 f2bf(float f) {
    union { float f; unsigned int u; } a; a.f = f;
    unsigned int u = a.u + 0x7FFFu + ((a.u >> 16) & 1u);  // RNE
    return (u16)(u >> 16);
}
__device__ __forceinline__ float bf2f(u16 v) {
    union { unsigned int u; float f; } a; a.u = ((unsigned int)v) << 16;
    return a.f;
}
__device__ __forceinline__ ushort2 pkbf(float a, float b) {
    union { __hip_bfloat162 h; ushort2 u; } cv;
    cv.h = __float22bfloat162_rn(make_float2(a, b));
    return cv.u;
}
__device__ __forceinline__ void async_copy16(u16* lds, const u16* g) {
    __builtin_amdgcn_global_load_lds(
        (const __attribute__((address_space(1))) void*)g,
        (__attribute__((address_space(3))) void*)lds, 16, 0, 0);
}

// ================= fused setup: zero counts/degf + cvt Wl + cvt W1 =========
__global__ void k_setup(int* __restrict__ counts, float* __restrict__ degf,
                        const float* __restrict__ Wl, u16* __restrict__ WlT,
                        const float* __restrict__ W1, u16* __restrict__ W1T) {
    int b = blockIdx.x, t = threadIdx.x;
    if (b < 196) {
        int i = b * 256 + t;
        if (i < NN) { counts[i] = 0; degf[i] = 0.f; }
    } else if (b < 196 + 1024) {
        __shared__ float sm[32][33];
        int bb = b - 196;
        int n0 = (bb & 31) * 32, k0 = (bb >> 5) * 32;
        int ty = t >> 5, tx = t & 31;
        #pragma unroll
        for (int i = 0; i < 4; i++)
            sm[ty + i * 8][tx] = Wl[(size_t)(k0 + ty + i * 8) * LM + n0 + tx];
        __syncthreads();
        #pragma unroll
        for (int i = 0; i < 4; i++)
            WlT[(size_t)(n0 + ty + i * 8) * LM + k0 + tx] = f2bf(sm[tx][ty + i * 8]);
    } else {
        int idx = (b - 1220) * 256 + t;  // HC*LM, output-major
        if (idx < HC * LM) {
            int o = idx >> 10, k = idx & 1023;
            W1T[idx] = f2bf(W1[(size_t)k * HC + o]);
        }
    }
}

// ================= CSR build =================
__global__ void k_count(const int* __restrict__ ei, const float* __restrict__ ew,
                        int* __restrict__ counts, float* __restrict__ degf) {
    int e = blockIdx.x * 256 + threadIdx.x;
    if (e < NE) {
        int d = ei[NE + e];
        atomicAdd(&counts[d], 1);
        atomicAdd(&degf[d], ew[e]);
    }
}
__global__ void k_scan1(const int* __restrict__ counts, int* __restrict__ incl,
                        int* __restrict__ bsum) {
    __shared__ int sm[1024];
    int t = threadIdx.x, idx = blockIdx.x * 1024 + t;
    int v = (idx < NN) ? counts[idx] : 0;
    sm[t] = v; __syncthreads();
    for (int off = 1; off < 1024; off <<= 1) {
        int add = (t >= off) ? sm[t - off] : 0;
        __syncthreads();
        sm[t] += add;
        __syncthreads();
    }
    if (idx < NN) incl[idx] = sm[t];
    if (t == 1023) bsum[blockIdx.x] = sm[t];
}
// rowptr/cursor/dis; block-sum prefix computed in-wave (merges old scan2)
__global__ void k_scan3(const int* __restrict__ incl, const int* __restrict__ counts,
                        const int* __restrict__ bsum, const float* __restrict__ degf,
                        int* __restrict__ rowptr, int* __restrict__ cursor,
                        float* __restrict__ dis) {
    int seg = blockIdx.x >> 2;  // 1024-segment of this block (256*4=1024)
    int lane = threadIdx.x & 63;
    int v = (lane < seg) ? bsum[lane] : 0;  // seg <= 48 < 64
    #pragma unroll
    for (int off = 32; off > 0; off >>= 1) v += __shfl_down(v, off, 64);
    int boffv = __shfl(v, 0, 64);
    int idx = blockIdx.x * 256 + threadIdx.x;
    if (idx < NN) {
        int rp = incl[idx] - counts[idx] + boffv;
        rowptr[idx] = rp;
        cursor[idx] = rp;
        dis[idx] = rsqrtf(1.0f + degf[idx]);
    } else if (idx == NN) {
        rowptr[NN] = NE;
    }
}
// fill CSR; dis[src] folded into weight here (wnorm kernel removed)
__global__ void k_fill(const int* __restrict__ ei, const float* __restrict__ ew,
                       const float* __restrict__ dis,
                       int* __restrict__ cursor, int2* __restrict__ meta) {
    int e = blockIdx.x * 256 + threadIdx.x;
    if (e < NE) {
        int s = ei[e];
        int d = ei[NE + e];
        int slot = atomicAdd(&cursor[d], 1);
        meta[slot] = make_int2(s, __float_as_int(ew[e] * dis[s]));
    }
}

// ======== GEMM1: h = relu(x_out@Wl + x*Wa + c*Wc + bl), 128x256 tile ========
// One A-tile (fp32->bf16 reg-prefetch staging) feeds TWO async-staged B-tiles:
// halves per-FLOP staging VALU + barriers vs R3's 128x128. XOR-swizzled LDS
// (R1: conflicts 0). XCD swizzle: 4 n-siblings of an m-band get ids == mod 8.
__global__ __launch_bounds__(256, 2) void k_gemm1(
    const float* __restrict__ A32, const u16* __restrict__ Bt, u16* __restrict__ Cout,
    const float* __restrict__ xv, const float* __restrict__ cv,
    const float* __restrict__ Wa, const float* __restrict__ Wc,
    const float* __restrict__ bl) {
    __shared__ u16 lA[128 * 64];
    __shared__ u16 lB[2][128 * 64];
    const int tid = threadIdx.x;
    const int lane = tid & 63, wv = tid >> 6;
    const int bx = ((blockIdx.x >> 5) << 3) | (blockIdx.x & 7);
    const int by = (blockIdx.x >> 3) & 3;
    if (bx >= 391) return;   // uniform, before any barrier
    const int m0 = bx * 128, n0 = by * 256;
    const int wm = (wv >> 1) * 64, wn = (wv & 1) * 64;
    const int fr = lane & 15, qd = lane >> 4;

    f32x4 acc[2][4][4] = {};

    int srl[4], sslot[4]; const float* sbase[4];
    float4 pf[8];
    #pragma unroll
    for (int i = 0; i < 4; i++) {
        int cidx = i * 256 + tid;
        srl[i] = cidx >> 3; sslot[i] = cidx & 7;
        int k8 = sslot[i] ^ (srl[i] & 7);
        int row = m0 + srl[i]; if (row >= NN) row = NN - 1;
        sbase[i] = A32 + (size_t)row * LM + k8 * 8;
    }
    #pragma unroll
    for (int i = 0; i < 4; i++) {            // prefetch tile 0
        pf[2 * i]     = *(const float4*)(sbase[i]);
        pf[2 * i + 1] = *(const float4*)(sbase[i] + 4);
    }

    for (int kt = 0; kt < 16; kt++) {
        const int k0 = kt << 6;
        __syncthreads();
        #pragma unroll
        for (int h = 0; h < 2; h++)
            #pragma unroll
            for (int i = 0; i < 4; i++) {
                int r0 = i * 32 + wv * 8;
                int rl = r0 + (lane >> 3);
                int slot = lane & 7;
                int k8 = slot ^ (rl & 7);
                const u16* g = Bt + (size_t)(n0 + h * 128 + rl) * LM + k0 + k8 * 8;
                async_copy16(&lB[h][r0 * 64], g);
            }
        #pragma unroll
        for (int i = 0; i < 4; i++) {
            union { ushort2 u2[4]; bf16x8 v; } pk;
            pk.u2[0] = pkbf(pf[2 * i].x, pf[2 * i].y);
            pk.u2[1] = pkbf(pf[2 * i].z, pf[2 * i].w);
            pk.u2[2] = pkbf(pf[2 * i + 1].x, pf[2 * i + 1].y);
            pk.u2[3] = pkbf(pf[2 * i + 1].z, pf[2 * i + 1].w);
            *(bf16x8*)&lA[srl[i] * 64 + sslot[i] * 8] = pk.v;
        }
        __syncthreads();
        if (kt < 15) {   // prefetch next tile; MFMA below hides latency
            #pragma unroll
            for (int i = 0; i < 4; i++) {
                pf[2 * i]     = *(const float4*)(sbase[i] + k0 + 64);
                pf[2 * i + 1] = *(const float4*)(sbase[i] + k0 + 68);
            }
        }
        #pragma unroll
        for (int s = 0; s < 2; s++) {
            const int slot = (s * 4 + qd) ^ (fr & 7);
            bf16x8 af[4];
            #pragma unroll
            for (int mi = 0; mi < 4; mi++)
                af[mi] = *(const bf16x8*)&lA[(wm + mi * 16 + fr) * 64 + slot * 8];
            #pragma unroll
            for (int h = 0; h < 2; h++) {
                bf16x8 bfm[4];
                #pragma unroll
                for (int ni = 0; ni < 4; ni++)
                    bfm[ni] = *(const bf16x8*)&lB[h][(wn + ni * 16 + fr) * 64 + slot * 8];
                #pragma unroll
                for (int mi = 0; mi < 4; mi++)
                    #pragma unroll
                    for (int ni = 0; ni < 4; ni++)
                        acc[h][mi][ni] = __builtin_amdgcn_mfma_f32_16x16x32_bf16(
                            af[mi], bfm[ni], acc[h][mi][ni], 0, 0, 0);
            }
        }
    }

    #pragma unroll
    for (int h = 0; h < 2; h++) {
        int jj[4]; float waj[4], wcj[4], blj[4];
        #pragma unroll
        for (int ni = 0; ni < 4; ni++) {
            jj[ni] = n0 + h * 128 + wn + ni * 16 + fr;
            waj[ni] = Wa[jj[ni]]; wcj[ni] = Wc[jj[ni]]; blj[ni] = bl[jj[ni]];
        }
        #pragma unroll
        for (int mi = 0; mi < 4; mi++)
            #pragma unroll
            for (int r = 0; r < 4; r++) {
                int row = m0 + wm + mi * 16 + qd * 4 + r;
                if (row < NN) {
                    float xb = xv[row], cb = cv[row];
                    #pragma unroll
                    for (int ni = 0; ni < 4; ni++) {
                        float v = acc[h][mi][ni][r] + xb * waj[ni] + cb * wcj[ni] + blj[ni];
                        Cout[(size_t)row * LM + jj[ni]] = f2bf(fmaxf(v, 0.f));
                    }
                }
            }
    }
}

// ======== GEMM2: y1 = h @ W1, 64x128 tile (782 blocks, 24KB LDS) ========
__global__ __launch_bounds__(256) void k_gemm2(
    const u16* __restrict__ Abf, const u16* __restrict__ Bt, u16* __restrict__ Cout) {
    __shared__ u16 lA[64 * 64];
    __shared__ u16 lB[128 * 64];
    const int tid = threadIdx.x;
    const int lane = tid & 63, wv = tid >> 6;
    const int m0 = blockIdx.x * 64;
    const int wm = (wv >> 1) * 32, wn = (wv & 1) * 64;
    const int fr = lane & 15, qd = lane >> 4;
    f32x4 acc[2][4] = {};

    for (int kt = 0; kt < 16; kt++) {
        const int k0 = kt << 6;
        __syncthreads();
        #pragma unroll
        for (int i = 0; i < 4; i++) {   // B: 128 rows (N=128 exact)
            int r0 = i * 32 + wv * 8;
            int rl = r0 + (lane >> 3);
            int slot = lane & 7;
            int k8 = slot ^ (rl & 7);
            const u16* g = Bt + (size_t)rl * LM + k0 + k8 * 8;
            async_copy16(&lB[r0 * 64], g);
        }
        #pragma unroll
        for (int i = 0; i < 2; i++) {   // A: 64 rows
            int r0 = i * 32 + wv * 8;
            int rl = r0 + (lane >> 3);
            int slot = lane & 7;
            int k8 = slot ^ (rl & 7);
            int row = m0 + rl; if (row >= NN) row = NN - 1;
            const u16* g = Abf + (size_t)row * LM + k0 + k8 * 8;
            async_copy16(&lA[r0 * 64], g);
        }
        __syncthreads();
        #pragma unroll
        for (int s = 0; s < 2; s++) {
            const int slot = (s * 4 + qd) ^ (fr & 7);
            bf16x8 af[2], bfm[4];
            #pragma unroll
            for (int mi = 0; mi < 2; mi++)
                af[mi] = *(const bf16x8*)&lA[(wm + mi * 16 + fr) * 64 + slot * 8];
            #pragma unroll
            for (int ni = 0; ni < 4; ni++)
                bfm[ni] = *(const bf16x8*)&lB[(wn + ni * 16 + fr) * 64 + slot * 8];
            #pragma unroll
            for (int mi = 0; mi < 2; mi++)
                #pragma unroll
                for (int ni = 0; ni < 4; ni++)
                    acc[mi][ni] = __builtin_amdgcn_mfma_f32_16x16x32_bf16(
                        af[mi], bfm[ni], acc[mi][ni], 0, 0, 0);
        }
    }
    #pragma unroll
    for (int mi = 0; mi < 2; mi++)
        #pragma unroll
        for (int r = 0; r < 4; r++) {
            int row = m0 + wm + mi * 16 + qd * 4 + r;
            if (row < NN) {
                #pragma unroll
                for (int ni = 0; ni < 4; ni++)
                    Cout[(size_t)row * HC + wn + ni * 16 + fr] = f2bf(acc[mi][ni][r]);
            }
        }
}

// ====== fused agg1 + gemm3: per node, h1 = relu(Anorm@y1 + b1); y3 = h1@W3 ======
__global__ __launch_bounds__(512) void k_agg1g3(
    const u16* __restrict__ y1, const int* __restrict__ rowptr,
    const int2* __restrict__ meta, const float* __restrict__ dis,
    const float* __restrict__ b1, const float* __restrict__ W3,
    u16* __restrict__ y3) {
    __shared__ float hrow[8][HC];
    int wv = threadIdx.x >> 6, lane = threadIdx.x & 63;
    int node = blockIdx.x * 8 + wv;
    if (node >= NN) return;
    float di = dis[node];
    int p0 = rowptr[node], p1 = rowptr[node + 1];
    ushort2 sv = *(const ushort2*)(y1 + (size_t)node * HC + lane * 2);
    float a0 = di * bf2f(sv.x), a1 = di * bf2f(sv.y);
    #pragma unroll 8
    for (int p = p0; p < p1; ++p) {
        int2 m = meta[p];
        float nm = __int_as_float(m.y);
        ushort2 v = *(const ushort2*)(y1 + (size_t)m.x * HC + lane * 2);
        a0 += nm * bf2f(v.x);
        a1 += nm * bf2f(v.y);
    }
    a0 = fmaxf(di * a0 + b1[lane * 2], 0.f);
    a1 = fmaxf(di * a1 + b1[lane * 2 + 1], 0.f);
    hrow[wv][lane * 2] = a0;
    hrow[wv][lane * 2 + 1] = a1;
    // wave-synchronous LDS use: no barrier needed
    float acc = 0.f;
    #pragma unroll 8
    for (int k = 0; k < HC; ++k)
        acc += hrow[wv][k] * W3[(size_t)k * OC + lane];
    y3[(size_t)node * OC + lane] = f2bf(acc);
}

// ================= aggregation 3: out = Anorm @ y3 + b3, OC=64 =================
__global__ __launch_bounds__(256) void k_agg3(
    const u16* __restrict__ y3, const int* __restrict__ rowptr,
    const int2* __restrict__ meta, const float* __restrict__ dis,
    const float* __restrict__ b3, float* __restrict__ outp) {
    int node = blockIdx.x * 4 + (threadIdx.x >> 6);
    int lane = threadIdx.x & 63;
    if (node >= NN) return;
    float di = dis[node];
    int p0 = rowptr[node], p1 = rowptr[node + 1];
    float a = di * bf2f(y3[(size_t)node * OC + lane]);
    #pragma unroll 8
    for (int p = p0; p < p1; ++p) {
        int2 m = meta[p];
        a += __int_as_float(m.y) * bf2f(y3[(size_t)m.x * OC + lane]);
    }
    outp[(size_t)node * OC + lane] = di * a + b3[lane];
}

extern "C" void kernel_launch(void* const* d_in, const int* in_sizes, int n_in,
                              void* d_out, int out_size, void* d_ws, size_t ws_size,
                              hipStream_t stream) {
    const float* x    = (const float*)d_in[0];
    const float* xout = (const float*)d_in[1];
    const float* c    = (const float*)d_in[2];
    const int*   ei   = (const int*)d_in[3];
    const float* ew   = (const float*)d_in[4];
    const float* Wa   = (const float*)d_in[5];
    const float* Wc   = (const float*)d_in[6];
    const float* Wl   = (const float*)d_in[7];
    const float* bl   = (const float*)d_in[8];
    const float* W1   = (const float*)d_in[9];
    const float* b1   = (const float*)d_in[10];
    const float* W3   = (const float*)d_in[11];
    const float* b3   = (const float*)d_in[12];
    float* outp = (float*)d_out;

    char* ws = (char*)d_ws;
    int*   rowptr = (int*)(ws + OFF_ROWPTR);
    int*   cursor = (int*)(ws + OFF_CURSOR);
    int*   counts = (int*)(ws + OFF_COUNTS);
    int*   incl   = (int*)(ws + OFF_INCL);
    int*   bsum   = (int*)(ws + OFF_BSUM);
    float* dis    = (float*)(ws + OFF_DIS);
    int2*  meta   = (int2*)(ws + OFF_META);
    u16*   WlT    = (u16*)(ws + OFF_WLT);
    u16*   W1T    = (u16*)(ws + OFF_W1T);
    u16*   hbuf   = (u16*)(ws + OFF_H);
    u16*   y1     = (u16*)(ws + OFF_Y1);
    float* degf   = (float*)(ws + OFF_DEGF);
    u16*   y3     = (u16*)(ws + OFF_Y3);

    k_setup<<<1732, 256, 0, stream>>>(counts, degf, Wl, WlT, W1, W1T);
    k_count<<<3125, 256, 0, stream>>>(ei, ew, counts, degf);
    k_scan1<<<49, 1024, 0, stream>>>(counts, incl, bsum);
    k_scan3<<<196, 256, 0, stream>>>(incl, counts, bsum, degf, rowptr, cursor, dis);
    k_fill <<<3125, 256, 0, stream>>>(ei, ew, dis, cursor, meta);

    // GEMM1: 128x256 tiles; grid = ceil(391/8)*8 m-groups * 4 n = 49*32
    k_gemm1<<<49 * 32, 256, 0, stream>>>(xout, WlT, hbuf, x, c, Wa, Wc, bl);
    // GEMM2: 64x128 tiles
    k_gemm2<<<782, 256, 0, stream>>>(hbuf, W1T, y1);
    // conv1 aggregation + bias + relu + conv3 linear (fused)
    k_agg1g3<<<6250, 512, 0, stream>>>(y1, rowptr, meta, dis, b1, W3, y3);
    // conv3 aggregation + bias -> out
    k_agg3<<<12500, 256, 0, stream>>>(y3, rowptr, meta, dis, b3, outp);
}

// Round 6
// 662.747 us; speedup vs baseline: 1.2999x; 1.0677x over previous
//
#include <hip/hip_runtime.h>
#include <hip/hip_bf16.h>

typedef unsigned short u16;
typedef unsigned long long u64;
typedef __attribute__((ext_vector_type(8))) short bf16x8;
typedef __attribute__((ext_vector_type(4))) float f32x4;

constexpr int NN = 50000;   // nodes
constexpr int NE = 800000;  // edges
constexpr int LM = 1024;
constexpr int HC = 128;
constexpr int OC = 64;

// ---- workspace layout (bytes) ----
constexpr size_t OFF_ROWPTR = 0;          // (NN+1) int
constexpr size_t OFF_CURSOR = 200192;     // NN int
constexpr size_t OFF_PK     = 400384;     // NN u64 (count<<48 | fx32 weight sum)
constexpr size_t OFF_INCL   = 800512;     // NN int
constexpr size_t OFF_BSUM   = 1000704;    // 64 int
constexpr size_t OFF_DIS    = 1000960;    // NN float
constexpr size_t OFF_META   = 1201152;    // NE int2 (src, w-bits)
constexpr size_t OFF_WLT    = 7601408;    // LM*LM u16
constexpr size_t OFF_W1T    = 9698560;    // HC*LM u16
constexpr size_t OFF_H      = 9960704;    // NN*LM u16
constexpr size_t OFF_Y1     = 112360704;  // NN*HC u16
constexpr size_t OFF_Y3     = 125160704;  // NN*OC u16
constexpr size_t OFF_ABF    = 131560704;  // NN*LM u16 (fast path only)
constexpr size_t NEED_FAST  = OFF_ABF + (size_t)NN * LM * 2;  // ~234 MB

__device__ __forceinline__ u16 f2bf(float f) {
    union { float f; unsigned int u; } a; a.f = f;
    unsigned int u = a.u + 0x7FFFu + ((a.u >> 16) & 1u);  // RNE
    return (u16)(u >> 16);
}
__device__ __forceinline__ float bf2f(u16 v) {
    union { unsigned int u; float f; } a; a.u = ((unsigned int)v) << 16;
    return a.f;
}
__device__ __forceinline__ ushort2 pkbf(float a, float b) {
    union { __hip_bfloat162 h; ushort2 u; } cv;
    cv.h = __float22bfloat162_rn(make_float2(a, b));
    return cv.u;
}
__device__ __forceinline__ void async_copy16(u16* lds, const u16* g) {
    __builtin_amdgcn_global_load_lds(
        (const __attribute__((address_space(1))) void*)g,
        (__attribute__((address_space(3))) void*)lds, 16, 0, 0);
}

// ================= fused setup: zero pk + cvt Wl + cvt W1 =========
__global__ void k_setup(u64* __restrict__ pk,
                        const float* __restrict__ Wl, u16* __restrict__ WlT,
                        const float* __restrict__ W1, u16* __restrict__ W1T) {
    int b = blockIdx.x, t = threadIdx.x;
    if (b < 196) {
        int i = b * 256 + t;
        if (i < NN) pk[i] = 0ULL;
    } else if (b < 196 + 1024) {
        __shared__ float sm[32][33];
        int bb = b - 196;
        int n0 = (bb & 31) * 32, k0 = (bb >> 5) * 32;
        int ty = t >> 5, tx = t & 31;
        #pragma unroll
        for (int i = 0; i < 4; i++)
            sm[ty + i * 8][tx] = Wl[(size_t)(k0 + ty + i * 8) * LM + n0 + tx];
        __syncthreads();
        #pragma unroll
        for (int i = 0; i < 4; i++)
            WlT[(size_t)(n0 + ty + i * 8) * LM + k0 + tx] = f2bf(sm[tx][ty + i * 8]);
    } else {
        int idx = (b - 1220) * 256 + t;  // HC*LM, output-major
        if (idx < HC * LM) {
            int o = idx >> 10, k = idx & 1023;
            W1T[idx] = f2bf(W1[(size_t)k * HC + o]);
        }
    }
}

// ================= CSR build =================
// one u64 atomic per edge: count in [48,64), weight sum fixed-point 2^-32 in [0,48)
__global__ void k_count(const int* __restrict__ ei, const float* __restrict__ ew,
                        u64* __restrict__ pk) {
    int e = blockIdx.x * 256 + threadIdx.x;
    if (e < NE) {
        int d = ei[NE + e];
        u64 add = (1ULL << 48) | (u64)(ew[e] * 4294967296.0);
        atomicAdd(&pk[d], add);
    }
}
__global__ void k_scan1(const u64* __restrict__ pk, int* __restrict__ incl,
                        int* __restrict__ bsum) {
    __shared__ int sm[1024];
    int t = threadIdx.x, idx = blockIdx.x * 1024 + t;
    int v = (idx < NN) ? (int)(pk[idx] >> 48) : 0;
    sm[t] = v; __syncthreads();
    for (int off = 1; off < 1024; off <<= 1) {
        int add = (t >= off) ? sm[t - off] : 0;
        __syncthreads();
        sm[t] += add;
        __syncthreads();
    }
    if (idx < NN) incl[idx] = sm[t];
    if (t == 1023) bsum[blockIdx.x] = sm[t];
}
// rowptr/cursor/dis; block-sum prefix computed in-wave
__global__ void k_scan3(const int* __restrict__ incl, const u64* __restrict__ pk,
                        const int* __restrict__ bsum,
                        int* __restrict__ rowptr, int* __restrict__ cursor,
                        float* __restrict__ dis) {
    int seg = blockIdx.x >> 2;
    int lane = threadIdx.x & 63;
    int v = (lane < seg) ? bsum[lane] : 0;  // seg <= 48 < 64
    #pragma unroll
    for (int off = 32; off > 0; off >>= 1) v += __shfl_down(v, off, 64);
    int boffv = __shfl(v, 0, 64);
    int idx = blockIdx.x * 256 + threadIdx.x;
    if (idx < NN) {
        u64 p = pk[idx];
        int cnt = (int)(p >> 48);
        float deg = (float)((double)(p & 0xFFFFFFFFFFFFULL) * 2.3283064365386963e-10);
        int rp = incl[idx] - cnt + boffv;
        rowptr[idx] = rp;
        cursor[idx] = rp;
        dis[idx] = rsqrtf(1.0f + deg);
    } else if (idx == NN) {
        rowptr[NN] = NE;
    }
}
// fill CSR; dis[src] folded into weight
__global__ void k_fill(const int* __restrict__ ei, const float* __restrict__ ew,
                       const float* __restrict__ dis,
                       int* __restrict__ cursor, int2* __restrict__ meta) {
    int e = blockIdx.x * 256 + threadIdx.x;
    if (e < NE) {
        int s = ei[e];
        int d = ei[NE + e];
        int slot = atomicAdd(&cursor[d], 1);
        meta[slot] = make_int2(s, __float_as_int(ew[e] * dis[s]));
    }
}

// ================= x_out fp32 -> bf16 streaming convert (fast path) ==========
__global__ __launch_bounds__(256) void k_cvtA(const float* __restrict__ A32,
                                              u16* __restrict__ Abf) {
    size_t idx = (size_t)blockIdx.x * 256 + threadIdx.x;  // chunk of 8 elems
    const float* src = A32 + idx * 8;
    float4 v0 = *(const float4*)(src);
    float4 v1 = *(const float4*)(src + 4);
    union { ushort2 u2[4]; bf16x8 v; } pk;
    pk.u2[0] = pkbf(v0.x, v0.y);
    pk.u2[1] = pkbf(v0.z, v0.w);
    pk.u2[2] = pkbf(v1.x, v1.y);
    pk.u2[3] = pkbf(v1.z, v1.w);
    *(bf16x8*)(Abf + idx * 8) = pk.v;
}

// ======== GEMM1a (fast path): pure-async m97-style 128x128, fused epilogue ====
// Both operands bf16 via global_load_lds; XOR-swizzled LDS (R1: conflicts 0);
// XCD swizzle: 8 n-siblings of an m-band get ids == same mod 8.
__global__ __launch_bounds__(256, 2) void k_gemm1a(
    const u16* __restrict__ Abf, const u16* __restrict__ Bt, u16* __restrict__ Cout,
    const float* __restrict__ xv, const float* __restrict__ cv,
    const float* __restrict__ Wa, const float* __restrict__ Wc,
    const float* __restrict__ bl) {
    __shared__ u16 lA[128 * 64];
    __shared__ u16 lB[128 * 64];
    const int tid = threadIdx.x;
    const int lane = tid & 63, wv = tid >> 6;
    int x = blockIdx.x & 7, j = blockIdx.x >> 3;
    int bx = (j & ~7) | x;
    int by = j & 7;
    if (bx >= 391) return;  // uniform, before any barrier
    const int m0 = bx * 128, n0 = by * 128;
    const int wm = (wv >> 1) * 64, wn = (wv & 1) * 64;
    const int fr = lane & 15, qd = lane >> 4;

    f32x4 acc[4][4] = {};

    for (int kt = 0; kt < 16; kt++) {
        const int k0 = kt << 6;
        __syncthreads();
        #pragma unroll
        for (int i = 0; i < 4; i++) {
            int r0 = i * 32 + wv * 8;
            int rl = r0 + (lane >> 3);
            int slot = lane & 7;
            int k8 = slot ^ (rl & 7);
            const u16* g = Bt + (size_t)(n0 + rl) * LM + k0 + k8 * 8;
            async_copy16(&lB[r0 * 64], g);
        }
        #pragma unroll
        for (int i = 0; i < 4; i++) {
            int r0 = i * 32 + wv * 8;
            int rl = r0 + (lane >> 3);
            int slot = lane & 7;
            int k8 = slot ^ (rl & 7);
            int row = m0 + rl; if (row >= NN) row = NN - 1;
            const u16* g = Abf + (size_t)row * LM + k0 + k8 * 8;
            async_copy16(&lA[r0 * 64], g);
        }
        __syncthreads();
        #pragma unroll
        for (int s = 0; s < 2; s++) {
            const int slot = (s * 4 + qd) ^ (fr & 7);
            bf16x8 af[4], bfm[4];
            #pragma unroll
            for (int mi = 0; mi < 4; mi++)
                af[mi] = *(const bf16x8*)&lA[(wm + mi * 16 + fr) * 64 + slot * 8];
            #pragma unroll
            for (int ni = 0; ni < 4; ni++)
                bfm[ni] = *(const bf16x8*)&lB[(wn + ni * 16 + fr) * 64 + slot * 8];
            #pragma unroll
            for (int mi = 0; mi < 4; mi++)
                #pragma unroll
                for (int ni = 0; ni < 4; ni++)
                    acc[mi][ni] = __builtin_amdgcn_mfma_f32_16x16x32_bf16(
                        af[mi], bfm[ni], acc[mi][ni], 0, 0, 0);
        }
    }

    int jj[4]; float waj[4], wcj[4], blj[4];
    #pragma unroll
    for (int ni = 0; ni < 4; ni++) {
        jj[ni] = n0 + wn + ni * 16 + fr;
        waj[ni] = Wa[jj[ni]]; wcj[ni] = Wc[jj[ni]]; blj[ni] = bl[jj[ni]];
    }
    #pragma unroll
    for (int mi = 0; mi < 4; mi++)
        #pragma unroll
        for (int r = 0; r < 4; r++) {
            int row = m0 + wm + mi * 16 + qd * 4 + r;
            if (row < NN) {
                float xb = xv[row], cb = cv[row];
                #pragma unroll
                for (int ni = 0; ni < 4; ni++) {
                    float v = acc[mi][ni][r] + xb * waj[ni] + cb * wcj[ni] + blj[ni];
                    Cout[(size_t)row * LM + jj[ni]] = f2bf(fmaxf(v, 0.f));
                }
            }
        }
}

// ======== GEMM1f (fallback): 128x256 tile, fp32 A reg-prefetch staging ========
__global__ __launch_bounds__(256, 2) void k_gemm1f(
    const float* __restrict__ A32, const u16* __restrict__ Bt, u16* __restrict__ Cout,
    const float* __restrict__ xv, const float* __restrict__ cv,
    const float* __restrict__ Wa, const float* __restrict__ Wc,
    const float* __restrict__ bl) {
    __shared__ u16 lA[128 * 64];
    __shared__ u16 lB[2][128 * 64];
    const int tid = threadIdx.x;
    const int lane = tid & 63, wv = tid >> 6;
    const int bx = ((blockIdx.x >> 5) << 3) | (blockIdx.x & 7);
    const int by = (blockIdx.x >> 3) & 3;
    if (bx >= 391) return;
    const int m0 = bx * 128, n0 = by * 256;
    const int wm = (wv >> 1) * 64, wn = (wv & 1) * 64;
    const int fr = lane & 15, qd = lane >> 4;

    f32x4 acc[2][4][4] = {};

    int srl[4], sslot[4]; const float* sbase[4];
    float4 pf[8];
    #pragma unroll
    for (int i = 0; i < 4; i++) {
        int cidx = i * 256 + tid;
        srl[i] = cidx >> 3; sslot[i] = cidx & 7;
        int k8 = sslot[i] ^ (srl[i] & 7);
        int row = m0 + srl[i]; if (row >= NN) row = NN - 1;
        sbase[i] = A32 + (size_t)row * LM + k8 * 8;
    }
    #pragma unroll
    for (int i = 0; i < 4; i++) {
        pf[2 * i]     = *(const float4*)(sbase[i]);
        pf[2 * i + 1] = *(const float4*)(sbase[i] + 4);
    }

    for (int kt = 0; kt < 16; kt++) {
        const int k0 = kt << 6;
        __syncthreads();
        #pragma unroll
        for (int h = 0; h < 2; h++)
            #pragma unroll
            for (int i = 0; i < 4; i++) {
                int r0 = i * 32 + wv * 8;
                int rl = r0 + (lane >> 3);
                int slot = lane & 7;
                int k8 = slot ^ (rl & 7);
                const u16* g = Bt + (size_t)(n0 + h * 128 + rl) * LM + k0 + k8 * 8;
                async_copy16(&lB[h][r0 * 64], g);
            }
        #pragma unroll
        for (int i = 0; i < 4; i++) {
            union { ushort2 u2[4]; bf16x8 v; } pk;
            pk.u2[0] = pkbf(pf[2 * i].x, pf[2 * i].y);
            pk.u2[1] = pkbf(pf[2 * i].z, pf[2 * i].w);
            pk.u2[2] = pkbf(pf[2 * i + 1].x, pf[2 * i + 1].y);
            pk.u2[3] = pkbf(pf[2 * i + 1].z, pf[2 * i + 1].w);
            *(bf16x8*)&lA[srl[i] * 64 + sslot[i] * 8] = pk.v;
        }
        __syncthreads();
        if (kt < 15) {
            #pragma unroll
            for (int i = 0; i < 4; i++) {
                pf[2 * i]     = *(const float4*)(sbase[i] + k0 + 64);
                pf[2 * i + 1] = *(const float4*)(sbase[i] + k0 + 68);
            }
        }
        #pragma unroll
        for (int s = 0; s < 2; s++) {
            const int slot = (s * 4 + qd) ^ (fr & 7);
            bf16x8 af[4];
            #pragma unroll
            for (int mi = 0; mi < 4; mi++)
                af[mi] = *(const bf16x8*)&lA[(wm + mi * 16 + fr) * 64 + slot * 8];
            #pragma unroll
            for (int h = 0; h < 2; h++) {
                bf16x8 bfm[4];
                #pragma unroll
                for (int ni = 0; ni < 4; ni++)
                    bfm[ni] = *(const bf16x8*)&lB[h][(wn + ni * 16 + fr) * 64 + slot * 8];
                #pragma unroll
                for (int mi = 0; mi < 4; mi++)
                    #pragma unroll
                    for (int ni = 0; ni < 4; ni++)
                        acc[h][mi][ni] = __builtin_amdgcn_mfma_f32_16x16x32_bf16(
                            af[mi], bfm[ni], acc[h][mi][ni], 0, 0, 0);
            }
        }
    }

    #pragma unroll
    for (int h = 0; h < 2; h++) {
        int jj[4]; float waj[4], wcj[4], blj[4];
        #pragma unroll
        for (int ni = 0; ni < 4; ni++) {
            jj[ni] = n0 + h * 128 + wn + ni * 16 + fr;
            waj[ni] = Wa[jj[ni]]; wcj[ni] = Wc[jj[ni]]; blj[ni] = bl[jj[ni]];
        }
        #pragma unroll
        for (int mi = 0; mi < 4; mi++)
            #pragma unroll
            for (int r = 0; r < 4; r++) {
                int row = m0 + wm + mi * 16 + qd * 4 + r;
                if (row < NN) {
                    float xb = xv[row], cb = cv[row];
                    #pragma unroll
                    for (int ni = 0; ni < 4; ni++) {
                        float v = acc[h][mi][ni][r] + xb * waj[ni] + cb * wcj[ni] + blj[ni];
                        Cout[(size_t)row * LM + jj[ni]] = f2bf(fmaxf(v, 0.f));
                    }
                }
            }
    }
}

// ======== GEMM2: y1 = h @ W1, 64x128 tile ========
__global__ __launch_bounds__(256) void k_gemm2(
    const u16* __restrict__ Abf, const u16* __restrict__ Bt, u16* __restrict__ Cout) {
    __shared__ u16 lA[64 * 64];
    __shared__ u16 lB[128 * 64];
    const int tid = threadIdx.x;
    const int lane = tid & 63, wv = tid >> 6;
    const int m0 = blockIdx.x * 64;
    const int wm = (wv >> 1) * 32, wn = (wv & 1) * 64;
    const int fr = lane & 15, qd = lane >> 4;
    f32x4 acc[2][4] = {};

    for (int kt = 0; kt < 16; kt++) {
        const int k0 = kt << 6;
        __syncthreads();
        #pragma unroll
        for (int i = 0; i < 4; i++) {
            int r0 = i * 32 + wv * 8;
            int rl = r0 + (lane >> 3);
            int slot = lane & 7;
            int k8 = slot ^ (rl & 7);
            const u16* g = Bt + (size_t)rl * LM + k0 + k8 * 8;
            async_copy16(&lB[r0 * 64], g);
        }
        #pragma unroll
        for (int i = 0; i < 2; i++) {
            int r0 = i * 32 + wv * 8;
            int rl = r0 + (lane >> 3);
            int slot = lane & 7;
            int k8 = slot ^ (rl & 7);
            int row = m0 + rl; if (row >= NN) row = NN - 1;
            const u16* g = Abf + (size_t)row * LM + k0 + k8 * 8;
            async_copy16(&lA[r0 * 64], g);
        }
        __syncthreads();
        #pragma unroll
        for (int s = 0; s < 2; s++) {
            const int slot = (s * 4 + qd) ^ (fr & 7);
            bf16x8 af[2], bfm[4];
            #pragma unroll
            for (int mi = 0; mi < 2; mi++)
                af[mi] = *(const bf16x8*)&lA[(wm + mi * 16 + fr) * 64 + slot * 8];
            #pragma unroll
            for (int ni = 0; ni < 4; ni++)
                bfm[ni] = *(const bf16x8*)&lB[(wn + ni * 16 + fr) * 64 + slot * 8];
            #pragma unroll
            for (int mi = 0; mi < 2; mi++)
                #pragma unroll
                for (int ni = 0; ni < 4; ni++)
                    acc[mi][ni] = __builtin_amdgcn_mfma_f32_16x16x32_bf16(
                        af[mi], bfm[ni], acc[mi][ni], 0, 0, 0);
        }
    }
    #pragma unroll
    for (int mi = 0; mi < 2; mi++)
        #pragma unroll
        for (int r = 0; r < 4; r++) {
            int row = m0 + wm + mi * 16 + qd * 4 + r;
            if (row < NN) {
                #pragma unroll
                for (int ni = 0; ni < 4; ni++)
                    Cout[(size_t)row * HC + wn + ni * 16 + fr] = f2bf(acc[mi][ni][r]);
            }
        }
}

// ====== fused agg1 + gemm3 ======
__global__ __launch_bounds__(512) void k_agg1g3(
    const u16* __restrict__ y1, const int* __restrict__ rowptr,
    const int2* __restrict__ meta, const float* __restrict__ dis,
    const float* __restrict__ b1, const float* __restrict__ W3,
    u16* __restrict__ y3) {
    __shared__ float hrow[8][HC];
    int wv = threadIdx.x >> 6, lane = threadIdx.x & 63;
    int node = blockIdx.x * 8 + wv;
    if (node >= NN) return;
    float di = dis[node];
    int p0 = rowptr[node], p1 = rowptr[node + 1];
    ushort2 sv = *(const ushort2*)(y1 + (size_t)node * HC + lane * 2);
    float a0 = di * bf2f(sv.x), a1 = di * bf2f(sv.y);
    #pragma unroll 8
    for (int p = p0; p < p1; ++p) {
        int2 m = meta[p];
        float nm = __int_as_float(m.y);
        ushort2 v = *(const ushort2*)(y1 + (size_t)m.x * HC + lane * 2);
        a0 += nm * bf2f(v.x);
        a1 += nm * bf2f(v.y);
    }
    a0 = fmaxf(di * a0 + b1[lane * 2], 0.f);
    a1 = fmaxf(di * a1 + b1[lane * 2 + 1], 0.f);
    hrow[wv][lane * 2] = a0;
    hrow[wv][lane * 2 + 1] = a1;
    float acc = 0.f;
    #pragma unroll 8
    for (int k = 0; k < HC; ++k)
        acc += hrow[wv][k] * W3[(size_t)k * OC + lane];
    y3[(size_t)node * OC + lane] = f2bf(acc);
}

// ================= aggregation 3 =================
__global__ __launch_bounds__(256) void k_agg3(
    const u16* __restrict__ y3, const int* __restrict__ rowptr,
    const int2* __restrict__ meta, const float* __restrict__ dis,
    const float* __restrict__ b3, float* __restrict__ outp) {
    int node = blockIdx.x * 4 + (threadIdx.x >> 6);
    int lane = threadIdx.x & 63;
    if (node >= NN) return;
    float di = dis[node];
    int p0 = rowptr[node], p1 = rowptr[node + 1];
    float a = di * bf2f(y3[(size_t)node * OC + lane]);
    #pragma unroll 8
    for (int p = p0; p < p1; ++p) {
        int2 m = meta[p];
        a += __int_as_float(m.y) * bf2f(y3[(size_t)m.x * OC + lane]);
    }
    outp[(size_t)node * OC + lane] = di * a + b3[lane];
}

extern "C" void kernel_launch(void* const* d_in, const int* in_sizes, int n_in,
                              void* d_out, int out_size, void* d_ws, size_t ws_size,
                              hipStream_t stream) {
    const float* x    = (const float*)d_in[0];
    const float* xout = (const float*)d_in[1];
    const float* c    = (const float*)d_in[2];
    const int*   ei   = (const int*)d_in[3];
    const float* ew   = (const float*)d_in[4];
    const float* Wa   = (const float*)d_in[5];
    const float* Wc   = (const float*)d_in[6];
    const float* Wl   = (const float*)d_in[7];
    const float* bl   = (const float*)d_in[8];
    const float* W1   = (const float*)d_in[9];
    const float* b1   = (const float*)d_in[10];
    const float* W3   = (const float*)d_in[11];
    const float* b3   = (const float*)d_in[12];
    float* outp = (float*)d_out;

    char* ws = (char*)d_ws;
    int*   rowptr = (int*)(ws + OFF_ROWPTR);
    int*   cursor = (int*)(ws + OFF_CURSOR);
    u64*   pk     = (u64*)(ws + OFF_PK);
    int*   incl   = (int*)(ws + OFF_INCL);
    int*   bsum   = (int*)(ws + OFF_BSUM);
    float* dis    = (float*)(ws + OFF_DIS);
    int2*  meta   = (int2*)(ws + OFF_META);
    u16*   WlT    = (u16*)(ws + OFF_WLT);
    u16*   W1T    = (u16*)(ws + OFF_W1T);
    u16*   hbuf   = (u16*)(ws + OFF_H);
    u16*   y1     = (u16*)(ws + OFF_Y1);
    u16*   y3     = (u16*)(ws + OFF_Y3);
    u16*   Abf    = (u16*)(ws + OFF_ABF);

    k_setup<<<1732, 256, 0, stream>>>(pk, Wl, WlT, W1, W1T);
    k_count<<<3125, 256, 0, stream>>>(ei, ew, pk);
    k_scan1<<<49, 1024, 0, stream>>>(pk, incl, bsum);
    k_scan3<<<196, 256, 0, stream>>>(incl, pk, bsum, rowptr, cursor, dis);
    k_fill <<<3125, 256, 0, stream>>>(ei, ew, dis, cursor, meta);

    if (ws_size >= NEED_FAST) {
        // fast path: pre-convert A to bf16, then pure-async m97-style GEMM1
        k_cvtA  <<<25000, 256, 0, stream>>>(xout, Abf);
        k_gemm1a<<<392 * 8, 256, 0, stream>>>(Abf, WlT, hbuf, x, c, Wa, Wc, bl);
    } else {
        k_gemm1f<<<49 * 32, 256, 0, stream>>>(xout, WlT, hbuf, x, c, Wa, Wc, bl);
    }
    // GEMM2: y1 = h @ W1
    k_gemm2<<<782, 256, 0, stream>>>(hbuf, W1T, y1);
    // conv1 aggregation + bias + relu + conv3 linear (fused)
    k_agg1g3<<<6250, 512, 0, stream>>>(y1, rowptr, meta, dis, b1, W3, y3);
    // conv3 aggregation + bias -> out
    k_agg3<<<12500, 256, 0, stream>>>(y3, rowptr, meta, dis, b3, outp);
}